// Round 3
// baseline (5814.104 us; speedup 1.0000x reference)
//
#include <hip/hip_runtime.h>
#include <cstdint>

// Problem constants (fixed by setup_inputs()).
#define NLINKS 20000
#define NPATHS 20000
#define LSEQ   8
#define TITER  8
#define DD     64
#define GW     192          // 3*DD gate width
#define NB     ((NPATHS + 63) / 64)   // 313 blocks of 64 rows

// ---------------- Threefry-2x32 (exact JAX semantics) ----------------
__host__ __device__ static inline uint32_t rotl32(uint32_t x, unsigned r) {
  return (x << r) | (x >> (32u - r));
}

__host__ __device__ static inline void threefry2x32(uint32_t k0, uint32_t k1,
                                                    uint32_t c0, uint32_t c1,
                                                    uint32_t& o0, uint32_t& o1) {
  uint32_t ks0 = k0, ks1 = k1, ks2 = k0 ^ k1 ^ 0x1BD11BDAu;
  uint32_t x0 = c0 + ks0, x1 = c1 + ks1;
#define TF_R(r) { x0 += x1; x1 = rotl32(x1, r); x1 ^= x0; }
  TF_R(13) TF_R(15) TF_R(26) TF_R(6)  x0 += ks1; x1 += ks2 + 1u;
  TF_R(17) TF_R(29) TF_R(16) TF_R(24) x0 += ks2; x1 += ks0 + 2u;
  TF_R(13) TF_R(15) TF_R(26) TF_R(6)  x0 += ks0; x1 += ks1 + 3u;
  TF_R(17) TF_R(29) TF_R(16) TF_R(24) x0 += ks1; x1 += ks2 + 4u;
  TF_R(13) TF_R(15) TF_R(26) TF_R(6)  x0 += ks2; x1 += ks0 + 5u;
#undef TF_R
  o0 = x0; o1 = x1;
}

// bernoulli(key, 0.5, (20000,256)), flattened element j.
// jax_threefry_partitionable=True (default since JAX 0.5.0):
//   counter = 64-bit linear index j as (hi,lo)=(0,j); bits = o0 ^ o1.
__device__ static inline bool bern_keep(uint32_t key0, uint32_t key1, uint32_t j) {
  uint32_t o0, o1;
  threefry2x32(key0, key1, 0u, j, o0, o1);
  uint32_t bits = o0 ^ o1;
  float u = __uint_as_float((bits >> 9) | 0x3f800000u) - 1.0f;
  return u < 0.5f;
}

__device__ static inline float sigmoidf_(float x) { return 1.0f / (1.0f + expf(-x)); }
__device__ static inline float seluf_(float x) {
  const float sc = 1.0507009873554805f;
  const float al = 1.6732632423543772f;
  return x > 0.0f ? sc * x : sc * al * expm1f(x);
}

// ---------------- init: build initial states, zero m ----------------
__global__ void init_kernel(const float* __restrict__ cap,
                            const float* __restrict__ traffic,
                            float* __restrict__ link_state,
                            float* __restrict__ path_state,
                            float* __restrict__ m) {
  int i = blockIdx.x * blockDim.x + threadIdx.x;
  if (i < NLINKS * DD) {
    link_state[i] = ((i & 63) == 0) ? cap[i >> 6] : 0.0f;
    m[i] = 0.0f;
  }
  if (i < NPATHS * DD) {
    path_state[i] = ((i & 63) == 0) ? traffic[i >> 6] : 0.0f;
  }
}

// ---------------- path GRU: 8 steps, scatter h into m ----------------
// Reference GRU (note Python precedence): hh = tanh(xh + (r*h) @ Wh[:,2D:]).
// block = 384 threads (6 waves), 64 paths (lane = path).
// Phase 1: waves 0-3 -> accA,accB for gate cols [0,128);
//          waves 4-5 -> accA only for cand cols [128,192).
// Interphase: z -> x_lds, rh = r*h -> r_lds.
// Phase 2: waves 4-5 -> accC = rh @ Wh[:,128:], update h, scatter m.
__global__ __launch_bounds__(384, 1) void path_gru_kernel(
    const float* __restrict__ link_state,
    float* __restrict__ path_state,
    float* __restrict__ m,
    const int* __restrict__ links,
    const float* __restrict__ Wx,
    const float* __restrict__ Wh,
    const float* __restrict__ bias) {
  __shared__ float h_lds[64][65];
  __shared__ float x_lds[64][65];   // reused to hold z after phase 1
  __shared__ float r_lds[64][65];   // holds rh = r * h

  const int tid  = threadIdx.x;
  const int lane = tid & 63;
  const int w    = __builtin_amdgcn_readfirstlane(tid >> 6);
  const int p0   = blockIdx.x * 64;

  // load h rows
  for (int idx = tid; idx < 64 * 16; idx += 384) {
    int p = idx >> 4, c = idx & 15;
    float4 v = make_float4(0.f, 0.f, 0.f, 0.f);
    if (p0 + p < NPATHS)
      v = reinterpret_cast<const float4*>(path_state)[(p0 + p) * 16 + c];
    h_lds[p][c * 4 + 0] = v.x; h_lds[p][c * 4 + 1] = v.y;
    h_lds[p][c * 4 + 2] = v.z; h_lds[p][c * 4 + 3] = v.w;
  }

  const int jb = (w < 4) ? (w * 32) : (128 + (w - 4) * 32);

  for (int t = 0; t < LSEQ; ++t) {
    __syncthreads();  // prev phase-2 done (h/x/r reads+writes quiesced)
    // stage x = link_state[links[8p+t]]
    for (int idx = tid; idx < 64 * 16; idx += 384) {
      int p = idx >> 4, c = idx & 15;
      float4 v = make_float4(0.f, 0.f, 0.f, 0.f);
      if (p0 + p < NPATHS) {
        int li = links[(p0 + p) * LSEQ + t];
        v = reinterpret_cast<const float4*>(link_state)[li * 16 + c];
      }
      x_lds[p][c * 4 + 0] = v.x; x_lds[p][c * 4 + 1] = v.y;
      x_lds[p][c * 4 + 2] = v.z; x_lds[p][c * 4 + 3] = v.w;
    }
    __syncthreads();

    // phase 1
    float accA[32], accB[32];
#pragma unroll
    for (int jj = 0; jj < 32; ++jj) { accA[jj] = bias[jb + jj]; accB[jj] = 0.0f; }
    if (w < 4) {
#pragma unroll 4
      for (int k = 0; k < DD; ++k) {
        float xk = x_lds[lane][k];
        float hk = h_lds[lane][k];
        const float* wxp = &Wx[k * GW + jb];
        const float* whp = &Wh[k * GW + jb];
#pragma unroll
        for (int jj = 0; jj < 32; ++jj) {
          accA[jj] = fmaf(xk, wxp[jj], accA[jj]);
          accB[jj] = fmaf(hk, whp[jj], accB[jj]);
        }
      }
    } else {
#pragma unroll 4
      for (int k = 0; k < DD; ++k) {
        float xk = x_lds[lane][k];
        const float* wxp = &Wx[k * GW + jb];
#pragma unroll
        for (int jj = 0; jj < 32; ++jj)
          accA[jj] = fmaf(xk, wxp[jj], accA[jj]);
      }
    }
    __syncthreads();  // all x/h reads done; x_lds reusable for z

    if (w < 2) {
#pragma unroll
      for (int jj = 0; jj < 32; ++jj)
        x_lds[lane][jb + jj] = sigmoidf_(accA[jj] + accB[jj]);          // z
    } else if (w < 4) {
#pragma unroll
      for (int jj = 0; jj < 32; ++jj) {
        int hj = jb - 64 + jj;
        float r = sigmoidf_(accA[jj] + accB[jj]);
        r_lds[lane][hj] = r * h_lds[lane][hj];                          // rh
      }
    }
    __syncthreads();

    // phase 2
    if (w >= 4) {
      const int hb = (w - 4) * 32;
      float accC[32];
#pragma unroll
      for (int jj = 0; jj < 32; ++jj) accC[jj] = 0.0f;
#pragma unroll 4
      for (int k = 0; k < DD; ++k) {
        float rhk = r_lds[lane][k];
        const float* whp = &Wh[k * GW + 128 + hb];
#pragma unroll
        for (int jj = 0; jj < 32; ++jj)
          accC[jj] = fmaf(rhk, whp[jj], accC[jj]);
      }
      const bool valid = (p0 + lane) < NPATHS;
      int li = 0;
      if (valid) li = links[(p0 + lane) * LSEQ + t];
#pragma unroll 4
      for (int jj = 0; jj < 32; ++jj) {
        int j = hb + jj;
        float z    = x_lds[lane][j];
        float hold = h_lds[lane][j];
        float hh = tanhf(accA[jj] + accC[jj]);
        float hn = z * hold + (1.0f - z) * hh;
        h_lds[lane][j] = hn;
        if (valid) {
          atomicAdd(&m[li * DD + j], hn);
          if (t == LSEQ - 1) path_state[(p0 + lane) * DD + j] = hn;
        }
      }
    }
  }
}

// ---------------- link GRU: one step, consumes m, zeroes m ----------------
__global__ __launch_bounds__(384, 1) void link_gru_kernel(
    float* __restrict__ link_state,
    float* __restrict__ m,
    const float* __restrict__ Wx,
    const float* __restrict__ Wh,
    const float* __restrict__ bias) {
  __shared__ float h_lds[64][65];
  __shared__ float x_lds[64][65];
  __shared__ float r_lds[64][65];

  const int tid  = threadIdx.x;
  const int lane = tid & 63;
  const int w    = __builtin_amdgcn_readfirstlane(tid >> 6);
  const int l0   = blockIdx.x * 64;

  for (int idx = tid; idx < 64 * 16; idx += 384) {
    int p = idx >> 4, c = idx & 15;
    float4 hv = make_float4(0.f, 0.f, 0.f, 0.f);
    float4 xv = make_float4(0.f, 0.f, 0.f, 0.f);
    if (l0 + p < NLINKS) {
      hv = reinterpret_cast<const float4*>(link_state)[(l0 + p) * 16 + c];
      xv = reinterpret_cast<const float4*>(m)[(l0 + p) * 16 + c];
    }
    h_lds[p][c * 4 + 0] = hv.x; h_lds[p][c * 4 + 1] = hv.y;
    h_lds[p][c * 4 + 2] = hv.z; h_lds[p][c * 4 + 3] = hv.w;
    x_lds[p][c * 4 + 0] = xv.x; x_lds[p][c * 4 + 1] = xv.y;
    x_lds[p][c * 4 + 2] = xv.z; x_lds[p][c * 4 + 3] = xv.w;
  }
  __syncthreads();

  const int jb = (w < 4) ? (w * 32) : (128 + (w - 4) * 32);

  float accA[32], accB[32];
#pragma unroll
  for (int jj = 0; jj < 32; ++jj) { accA[jj] = bias[jb + jj]; accB[jj] = 0.0f; }
  if (w < 4) {
#pragma unroll 4
    for (int k = 0; k < DD; ++k) {
      float xk = x_lds[lane][k];
      float hk = h_lds[lane][k];
      const float* wxp = &Wx[k * GW + jb];
      const float* whp = &Wh[k * GW + jb];
#pragma unroll
      for (int jj = 0; jj < 32; ++jj) {
        accA[jj] = fmaf(xk, wxp[jj], accA[jj]);
        accB[jj] = fmaf(hk, whp[jj], accB[jj]);
      }
    }
  } else {
#pragma unroll 4
    for (int k = 0; k < DD; ++k) {
      float xk = x_lds[lane][k];
      const float* wxp = &Wx[k * GW + jb];
#pragma unroll
      for (int jj = 0; jj < 32; ++jj)
        accA[jj] = fmaf(xk, wxp[jj], accA[jj]);
    }
  }
  __syncthreads();

  if (w < 2) {
#pragma unroll
    for (int jj = 0; jj < 32; ++jj)
      x_lds[lane][jb + jj] = sigmoidf_(accA[jj] + accB[jj]);
  } else if (w < 4) {
#pragma unroll
    for (int jj = 0; jj < 32; ++jj) {
      int hj = jb - 64 + jj;
      float r = sigmoidf_(accA[jj] + accB[jj]);
      r_lds[lane][hj] = r * h_lds[lane][hj];
    }
  }
  __syncthreads();

  if (w >= 4) {
    const int hb = (w - 4) * 32;
    float accC[32];
#pragma unroll
    for (int jj = 0; jj < 32; ++jj) accC[jj] = 0.0f;
#pragma unroll 4
    for (int k = 0; k < DD; ++k) {
      float rhk = r_lds[lane][k];
      const float* whp = &Wh[k * GW + 128 + hb];
#pragma unroll
      for (int jj = 0; jj < 32; ++jj)
        accC[jj] = fmaf(rhk, whp[jj], accC[jj]);
    }
    const bool valid = (l0 + lane) < NLINKS;
#pragma unroll 4
    for (int jj = 0; jj < 32; ++jj) {
      int j = hb + jj;
      float z    = x_lds[lane][j];
      float hold = h_lds[lane][j];
      float hh = tanhf(accA[jj] + accC[jj]);
      float hn = z * hold + (1.0f - z) * hh;
      if (valid) {
        link_state[(l0 + lane) * DD + j] = hn;
        m[(l0 + lane) * DD + j] = 0.0f;   // ready for next iteration's scatter
      }
    }
  }
}

// ---------------- readout MLP with exact-JAX dropout ----------------
__global__ __launch_bounds__(256, 1) void mlp_kernel(
    const float* __restrict__ path_state,
    const float* __restrict__ W1, const float* __restrict__ b1,
    const float* __restrict__ W2, const float* __restrict__ b2,
    const float* __restrict__ W3, const float* __restrict__ b3,
    float* __restrict__ out,
    uint32_t k1a, uint32_t k1b, uint32_t k2a, uint32_t k2b) {
  __shared__ float hbuf[64][256];   // rotated column index -> conflict-free

  const int tid  = threadIdx.x;
  const int lane = tid & 63;
  const int w    = __builtin_amdgcn_readfirstlane(tid >> 6);
  const int p0   = blockIdx.x * 64;
  const bool valid = (p0 + lane) < NPATHS;
  const int prow = valid ? (p0 + lane) : 0;

  float ps[DD];
  {
    const float4* src = reinterpret_cast<const float4*>(path_state) + prow * 16;
#pragma unroll
    for (int c = 0; c < 16; ++c) {
      float4 v = src[c];
      ps[c * 4 + 0] = v.x; ps[c * 4 + 1] = v.y;
      ps[c * 4 + 2] = v.z; ps[c * 4 + 3] = v.w;
    }
  }

  const int cb = w * 64;
  const uint32_t base = (uint32_t)(p0 + lane) * 256u;
  float acc[64];

  // layer 1: (20000,64)@(64,256)
#pragma unroll
  for (int c = 0; c < 64; ++c) acc[c] = b1[cb + c];
#pragma unroll 2
  for (int k = 0; k < DD; ++k) {
    float pk = ps[k];
    const float* wp = &W1[k * 256 + cb];
#pragma unroll
    for (int c = 0; c < 64; ++c) acc[c] = fmaf(pk, wp[c], acc[c]);
  }
#pragma unroll 2
  for (int c = 0; c < 64; ++c) {
    int u = cb + c;
    float v = seluf_(acc[c]);
    bool keep = bern_keep(k1a, k1b, base + (uint32_t)u);
    hbuf[lane][(u + lane) & 255] = keep ? v * 2.0f : 0.0f;
  }
  __syncthreads();

  // layer 2: (20000,256)@(256,256)
#pragma unroll
  for (int c = 0; c < 64; ++c) acc[c] = b2[cb + c];
#pragma unroll 2
  for (int k = 0; k < 256; ++k) {
    float hk = hbuf[lane][(k + lane) & 255];
    const float* wp = &W2[k * 256 + cb];
#pragma unroll
    for (int c = 0; c < 64; ++c) acc[c] = fmaf(hk, wp[c], acc[c]);
  }
  __syncthreads();  // all reads of hbuf done before overwrite
#pragma unroll 2
  for (int c = 0; c < 64; ++c) {
    int u = cb + c;
    float v = seluf_(acc[c]);
    bool keep = bern_keep(k2a, k2b, base + (uint32_t)u);
    hbuf[lane][(u + lane) & 255] = keep ? v * 2.0f : 0.0f;
  }
  __syncthreads();

  // layer 3: (20000,256)@(256,1), relu
  if (w == 0) {
    float s = b3[0];
    for (int k = 0; k < 256; ++k)
      s = fmaf(hbuf[lane][(k + lane) & 255], W3[k], s);
    if (valid) out[p0 + lane] = s > 0.0f ? s : 0.0f;
  }
}

// ---------------- host ----------------
extern "C" void kernel_launch(void* const* d_in, const int* in_sizes, int n_in,
                              void* d_out, int out_size, void* d_ws, size_t ws_size,
                              hipStream_t stream) {
  const float* cap     = (const float*)d_in[0];
  const float* traffic = (const float*)d_in[1];
  const int*   links   = (const int*)d_in[2];
  // d_in[3]=paths, d_in[4]=seqs: structure is regular (repeat/tile), not needed.
  const float* pWx = (const float*)d_in[5];
  const float* pWh = (const float*)d_in[6];
  const float* pb  = (const float*)d_in[7];
  const float* eWx = (const float*)d_in[8];
  const float* eWh = (const float*)d_in[9];
  const float* eb  = (const float*)d_in[10];
  const float* W1  = (const float*)d_in[11];
  const float* b1  = (const float*)d_in[12];
  const float* W2  = (const float*)d_in[13];
  const float* b2  = (const float*)d_in[14];
  const float* W3  = (const float*)d_in[15];
  const float* b3  = (const float*)d_in[16];
  float* out = (float*)d_out;

  float* link_state = (float*)d_ws;
  float* path_state = link_state + NLINKS * DD;
  float* m          = path_state + NPATHS * DD;

  // k1, k2 = jax.random.split(jax.random.key(1)) with
  // jax_threefry_partitionable=True (default since JAX 0.5.0):
  //   iota_2x32_shape((2,)) -> counts (hi,lo) = (0,0), (0,1)
  //   k_i = both output words of threefry(key, (0, i))
  uint32_t k1a, k1b, k2a, k2b;
  threefry2x32(0u, 1u, 0u, 0u, k1a, k1b);
  threefry2x32(0u, 1u, 0u, 1u, k2a, k2b);

  init_kernel<<<(NLINKS * DD + 255) / 256, 256, 0, stream>>>(
      cap, traffic, link_state, path_state, m);

  for (int it = 0; it < TITER; ++it) {
    path_gru_kernel<<<NB, 384, 0, stream>>>(link_state, path_state, m, links,
                                            pWx, pWh, pb);
    link_gru_kernel<<<NB, 384, 0, stream>>>(link_state, m, eWx, eWh, eb);
  }

  mlp_kernel<<<NB, 256, 0, stream>>>(path_state, W1, b1, W2, b2, W3, b3, out,
                                     k1a, k1b, k2a, k2b);
}

// Round 4
// 4989.816 us; speedup vs baseline: 1.1652x; 1.1652x over previous
//
#include <hip/hip_runtime.h>
#include <cstdint>

// Problem constants (fixed by setup_inputs()).
#define NLINKS 20000
#define NPATHS 20000
#define LSEQ   8
#define TITER  8
#define DD     64
#define GW     192          // 3*DD gate width
#define NEDGE  (NPATHS * LSEQ)        // 160000
#define NB     ((NPATHS + 63) / 64)   // 313 blocks of 64 rows

// ---------------- Threefry-2x32 (exact JAX semantics) ----------------
__host__ __device__ static inline uint32_t rotl32(uint32_t x, unsigned r) {
  return (x << r) | (x >> (32u - r));
}

__host__ __device__ static inline void threefry2x32(uint32_t k0, uint32_t k1,
                                                    uint32_t c0, uint32_t c1,
                                                    uint32_t& o0, uint32_t& o1) {
  uint32_t ks0 = k0, ks1 = k1, ks2 = k0 ^ k1 ^ 0x1BD11BDAu;
  uint32_t x0 = c0 + ks0, x1 = c1 + ks1;
#define TF_R(r) { x0 += x1; x1 = rotl32(x1, r); x1 ^= x0; }
  TF_R(13) TF_R(15) TF_R(26) TF_R(6)  x0 += ks1; x1 += ks2 + 1u;
  TF_R(17) TF_R(29) TF_R(16) TF_R(24) x0 += ks2; x1 += ks0 + 2u;
  TF_R(13) TF_R(15) TF_R(26) TF_R(6)  x0 += ks0; x1 += ks1 + 3u;
  TF_R(17) TF_R(29) TF_R(16) TF_R(24) x0 += ks1; x1 += ks2 + 4u;
  TF_R(13) TF_R(15) TF_R(26) TF_R(6)  x0 += ks2; x1 += ks0 + 5u;
#undef TF_R
  o0 = x0; o1 = x1;
}

// bernoulli(key, 0.5, (20000,256)), flattened element j.
// jax_threefry_partitionable=True: counter (0, j), bits = o0 ^ o1.
__device__ static inline bool bern_keep(uint32_t key0, uint32_t key1, uint32_t j) {
  uint32_t o0, o1;
  threefry2x32(key0, key1, 0u, j, o0, o1);
  uint32_t bits = o0 ^ o1;
  float u = __uint_as_float((bits >> 9) | 0x3f800000u) - 1.0f;
  return u < 0.5f;
}

__device__ static inline float sigmoidf_(float x) { return 1.0f / (1.0f + expf(-x)); }
__device__ static inline float seluf_(float x) {
  const float sc = 1.0507009873554805f;
  const float al = 1.6732632423543772f;
  return x > 0.0f ? sc * x : sc * al * expm1f(x);
}

// ============================================================================
// GATHER MODE (fast path): seq_h + CSR, no float atomics.
// ============================================================================

// init: link_state from cap; seq_h row 7 = initial path_state; zero counts.
__global__ void init_gather_kernel(const float* __restrict__ cap,
                                   const float* __restrict__ traffic,
                                   float* __restrict__ link_state,
                                   float* __restrict__ seq_h,
                                   int* __restrict__ counts) {
  int i = blockIdx.x * blockDim.x + threadIdx.x;
  if (i < NLINKS * DD)
    link_state[i] = ((i & 63) == 0) ? cap[i >> 6] : 0.0f;
  if (i < NPATHS * DD) {
    int p = i >> 6, j = i & 63;
    seq_h[(p * LSEQ + (LSEQ - 1)) * DD + j] = (j == 0) ? traffic[p] : 0.0f;
  }
  if (i < NLINKS) counts[i] = 0;
}

__global__ void csr_hist_kernel(const int* __restrict__ links,
                                int* __restrict__ counts) {
  int e = blockIdx.x * blockDim.x + threadIdx.x;
  if (e < NEDGE) atomicAdd(&counts[links[e]], 1);
}

__global__ __launch_bounds__(1024, 1) void csr_scan_kernel(
    const int* __restrict__ counts,
    int* __restrict__ row_start,
    int* __restrict__ cursor) {
  __shared__ int sc[1024];
  const int i = threadIdx.x;
  const int base = i * 20;               // 1024*20 = 20480 >= 20000
  int s = 0;
  for (int j = 0; j < 20; ++j) {
    int r = base + j;
    if (r < NLINKS) s += counts[r];
  }
  sc[i] = s;
  __syncthreads();
  for (int off = 1; off < 1024; off <<= 1) {
    int v = (i >= off) ? sc[i - off] : 0;
    __syncthreads();
    sc[i] += v;
    __syncthreads();
  }
  int run = sc[i] - s;                   // exclusive prefix
  for (int j = 0; j < 20; ++j) {
    int r = base + j;
    if (r < NLINKS) {
      row_start[r] = run;
      cursor[r] = run;
      run += counts[r];
    }
  }
}

// fill: after this, cursor[l] == row end.
__global__ void csr_fill_kernel(const int* __restrict__ links,
                                int* __restrict__ cursor,
                                int* __restrict__ edges) {
  int e = blockIdx.x * blockDim.x + threadIdx.x;
  if (e < NEDGE) {
    int l = links[e];
    int pos = atomicAdd(&cursor[l], 1);
    edges[pos] = e;
  }
}

// path GRU (gather mode): 8 steps; h kept in LDS; per-step h stored to seq_h.
// Reference GRU (Python precedence): hh = tanh(xh + (r*h) @ Wh[:,2D:]).
// block = 384 threads (6 waves), 64 paths (lane = path).
//   waves 0-1: accA+accB cols [0,64)   -> z       (also x prefetch)
//   waves 2-3: accA+accB cols [64,128) -> rh      (also x prefetch)
//   waves 4-5: accA cols [128,192) -> a; seq store of h(t-1); then phase 2.
// Barriers: 2 per step.
__global__ __launch_bounds__(384, 1) void path_gru_gather_kernel(
    const float* __restrict__ link_state,
    float* __restrict__ seq_h,
    const int* __restrict__ links,
    const float* __restrict__ Wx,
    const float* __restrict__ Wh,
    const float* __restrict__ bias) {
  __shared__ float h_lds[64][65];
  __shared__ float x_lds[64][65];
  __shared__ float g_lds[64][193];  // z: [0,64), rh: [64,128), a: [128,192)

  const int tid  = threadIdx.x;
  const int lane = tid & 63;
  const int w    = __builtin_amdgcn_readfirstlane(tid >> 6);
  const int p0   = blockIdx.x * 64;

  // load h from seq row 7 (carried state)
  for (int idx = tid; idx < 1024; idx += 384) {
    int p = idx >> 4, c = idx & 15;
    int pr = (p0 + p < NPATHS) ? (p0 + p) : (NPATHS - 1);
    float4 v = reinterpret_cast<const float4*>(seq_h)[(pr * LSEQ + 7) * 16 + c];
    h_lds[p][c * 4 + 0] = v.x; h_lds[p][c * 4 + 1] = v.y;
    h_lds[p][c * 4 + 2] = v.z; h_lds[p][c * 4 + 3] = v.w;
  }

  const int jb = (w < 4) ? (w * 32) : (128 + (w - 4) * 32);
  float bA[32];
#pragma unroll
  for (int jj = 0; jj < 32; ++jj) bA[jj] = bias[jb + jj];

  // x[0] gather (waves 0-3: 4 float4 slots each thread)
  float4 pf[4];
  if (tid < 256) {
#pragma unroll
    for (int s = 0; s < 4; ++s) {
      int slot = tid + 256 * s;
      int p = slot >> 4, c = slot & 15;
      int pr = (p0 + p < NPATHS) ? (p0 + p) : (NPATHS - 1);
      int li = links[pr * LSEQ + 0];
      pf[s] = reinterpret_cast<const float4*>(link_state)[li * 16 + c];
    }
#pragma unroll
    for (int s = 0; s < 4; ++s) {
      int slot = tid + 256 * s;
      int p = slot >> 4, c = slot & 15;
      x_lds[p][c * 4 + 0] = pf[s].x; x_lds[p][c * 4 + 1] = pf[s].y;
      x_lds[p][c * 4 + 2] = pf[s].z; x_lds[p][c * 4 + 3] = pf[s].w;
    }
  }
  __syncthreads();

  for (int t = 0; t < LSEQ; ++t) {
    // waves 4-5: store h(t-1) (stable during phase 1) to seq_h, coalesced.
    if (w >= 4 && t > 0) {
#pragma unroll
      for (int s = 0; s < 8; ++s) {
        int slot = (tid - 256) + 128 * s;
        int p = slot >> 4, c = slot & 15;
        if (p0 + p < NPATHS) {
          float4 v = make_float4(h_lds[p][c * 4 + 0], h_lds[p][c * 4 + 1],
                                 h_lds[p][c * 4 + 2], h_lds[p][c * 4 + 3]);
          reinterpret_cast<float4*>(seq_h)[((p0 + p) * LSEQ + (t - 1)) * 16 + c] = v;
        }
      }
    }
    // waves 0-3: issue gather loads for x[t+1] (hidden under phase-1 matvec)
    if (tid < 256 && t < LSEQ - 1) {
#pragma unroll
      for (int s = 0; s < 4; ++s) {
        int slot = tid + 256 * s;
        int p = slot >> 4, c = slot & 15;
        int pr = (p0 + p < NPATHS) ? (p0 + p) : (NPATHS - 1);
        int li = links[pr * LSEQ + t + 1];
        pf[s] = reinterpret_cast<const float4*>(link_state)[li * 16 + c];
      }
    }

    // phase 1
    float accA[32], accB[32];
#pragma unroll
    for (int jj = 0; jj < 32; ++jj) { accA[jj] = bA[jj]; accB[jj] = 0.0f; }
    if (w < 4) {
#pragma unroll 4
      for (int k = 0; k < DD; ++k) {
        float xk = x_lds[lane][k];
        float hk = h_lds[lane][k];
        const float* wxp = &Wx[k * GW + jb];
        const float* whp = &Wh[k * GW + jb];
#pragma unroll
        for (int jj = 0; jj < 32; ++jj) {
          accA[jj] = fmaf(xk, wxp[jj], accA[jj]);
          accB[jj] = fmaf(hk, whp[jj], accB[jj]);
        }
      }
    } else {
#pragma unroll 4
      for (int k = 0; k < DD; ++k) {
        float xk = x_lds[lane][k];
        const float* wxp = &Wx[k * GW + jb];
#pragma unroll
        for (int jj = 0; jj < 32; ++jj)
          accA[jj] = fmaf(xk, wxp[jj], accA[jj]);
      }
    }

    // write gates into g_lds
    if (w < 2) {
#pragma unroll
      for (int jj = 0; jj < 32; ++jj)
        g_lds[lane][jb + jj] = sigmoidf_(accA[jj] + accB[jj]);           // z
    } else if (w < 4) {
#pragma unroll
      for (int jj = 0; jj < 32; ++jj) {
        int hj = jb - 64 + jj;
        float r = sigmoidf_(accA[jj] + accB[jj]);
        g_lds[lane][64 + hj] = r * h_lds[lane][hj];                      // rh
      }
    } else {
#pragma unroll
      for (int jj = 0; jj < 32; ++jj)
        g_lds[lane][jb + jj] = accA[jj];                                 // a (bias incl)
    }
    __syncthreads();  // barrier B: gates ready; phase-1 x/h reads done

    if (w >= 4) {
      // phase 2: accC = rh @ Wh[:,128:]; h update
      const int hb = (w - 4) * 32;
      float accC[32];
#pragma unroll
      for (int jj = 0; jj < 32; ++jj) accC[jj] = 0.0f;
#pragma unroll 4
      for (int k = 0; k < DD; ++k) {
        float rhk = g_lds[lane][64 + k];
        const float* whp = &Wh[k * GW + 128 + hb];
#pragma unroll
        for (int jj = 0; jj < 32; ++jj)
          accC[jj] = fmaf(rhk, whp[jj], accC[jj]);
      }
#pragma unroll 4
      for (int jj = 0; jj < 32; ++jj) {
        int j = hb + jj;
        float z    = g_lds[lane][j];
        float a    = g_lds[lane][128 + j];
        float hold = h_lds[lane][j];
        float hh = tanhf(a + accC[jj]);
        h_lds[lane][j] = z * hold + (1.0f - z) * hh;
      }
    } else if (t < LSEQ - 1) {
      // waves 0-3: write x[t+1] (x_lds free after barrier B)
#pragma unroll
      for (int s = 0; s < 4; ++s) {
        int slot = tid + 256 * s;
        int p = slot >> 4, c = slot & 15;
        x_lds[p][c * 4 + 0] = pf[s].x; x_lds[p][c * 4 + 1] = pf[s].y;
        x_lds[p][c * 4 + 2] = pf[s].z; x_lds[p][c * 4 + 3] = pf[s].w;
      }
    }
    __syncthreads();  // barrier A: h/x ready for next step
  }

  // final store: seq row 7 = h after step 7 (also the carried path_state)
  for (int idx = tid; idx < 1024; idx += 384) {
    int p = idx >> 4, c = idx & 15;
    if (p0 + p < NPATHS) {
      float4 v = make_float4(h_lds[p][c * 4 + 0], h_lds[p][c * 4 + 1],
                             h_lds[p][c * 4 + 2], h_lds[p][c * 4 + 3]);
      reinterpret_cast<float4*>(seq_h)[((p0 + p) * LSEQ + 7) * 16 + c] = v;
    }
  }
}

// link GRU (gather mode): m = sum over CSR edges of seq_h rows.
__global__ __launch_bounds__(384, 1) void link_gru_gather_kernel(
    float* __restrict__ link_state,
    const float* __restrict__ seq_h,
    const int* __restrict__ row_start,
    const int* __restrict__ row_end,
    const int* __restrict__ edges,
    const float* __restrict__ Wx,
    const float* __restrict__ Wh,
    const float* __restrict__ bias) {
  __shared__ float h_lds[64][65];
  __shared__ float x_lds[64][65];
  __shared__ float g_lds[64][193];

  const int tid  = threadIdx.x;
  const int lane = tid & 63;
  const int w    = __builtin_amdgcn_readfirstlane(tid >> 6);
  const int l0   = blockIdx.x * 64;

  for (int idx = tid; idx < 1024; idx += 384) {
    int p = idx >> 4, c = idx & 15;
    float4 hv = make_float4(0.f, 0.f, 0.f, 0.f);
    float4 xv = make_float4(0.f, 0.f, 0.f, 0.f);
    if (l0 + p < NLINKS) {
      hv = reinterpret_cast<const float4*>(link_state)[(l0 + p) * 16 + c];
      int rs = row_start[l0 + p], re = row_end[l0 + p];
      for (int i = rs; i < re; ++i) {
        int e = edges[i];
        float4 v = reinterpret_cast<const float4*>(seq_h)[e * 16 + c];
        xv.x += v.x; xv.y += v.y; xv.z += v.z; xv.w += v.w;
      }
    }
    h_lds[p][c * 4 + 0] = hv.x; h_lds[p][c * 4 + 1] = hv.y;
    h_lds[p][c * 4 + 2] = hv.z; h_lds[p][c * 4 + 3] = hv.w;
    x_lds[p][c * 4 + 0] = xv.x; x_lds[p][c * 4 + 1] = xv.y;
    x_lds[p][c * 4 + 2] = xv.z; x_lds[p][c * 4 + 3] = xv.w;
  }
  __syncthreads();

  const int jb = (w < 4) ? (w * 32) : (128 + (w - 4) * 32);

  float accA[32], accB[32];
#pragma unroll
  for (int jj = 0; jj < 32; ++jj) { accA[jj] = bias[jb + jj]; accB[jj] = 0.0f; }
  if (w < 4) {
#pragma unroll 4
    for (int k = 0; k < DD; ++k) {
      float xk = x_lds[lane][k];
      float hk = h_lds[lane][k];
      const float* wxp = &Wx[k * GW + jb];
      const float* whp = &Wh[k * GW + jb];
#pragma unroll
      for (int jj = 0; jj < 32; ++jj) {
        accA[jj] = fmaf(xk, wxp[jj], accA[jj]);
        accB[jj] = fmaf(hk, whp[jj], accB[jj]);
      }
    }
  } else {
#pragma unroll 4
    for (int k = 0; k < DD; ++k) {
      float xk = x_lds[lane][k];
      const float* wxp = &Wx[k * GW + jb];
#pragma unroll
      for (int jj = 0; jj < 32; ++jj)
        accA[jj] = fmaf(xk, wxp[jj], accA[jj]);
    }
  }

  if (w < 2) {
#pragma unroll
    for (int jj = 0; jj < 32; ++jj)
      g_lds[lane][jb + jj] = sigmoidf_(accA[jj] + accB[jj]);
  } else if (w < 4) {
#pragma unroll
    for (int jj = 0; jj < 32; ++jj) {
      int hj = jb - 64 + jj;
      float r = sigmoidf_(accA[jj] + accB[jj]);
      g_lds[lane][64 + hj] = r * h_lds[lane][hj];
    }
  } else {
#pragma unroll
    for (int jj = 0; jj < 32; ++jj)
      g_lds[lane][jb + jj] = accA[jj];
  }
  __syncthreads();

  if (w >= 4) {
    const int hb = (w - 4) * 32;
    float accC[32];
#pragma unroll
    for (int jj = 0; jj < 32; ++jj) accC[jj] = 0.0f;
#pragma unroll 4
    for (int k = 0; k < DD; ++k) {
      float rhk = g_lds[lane][64 + k];
      const float* whp = &Wh[k * GW + 128 + hb];
#pragma unroll
      for (int jj = 0; jj < 32; ++jj)
        accC[jj] = fmaf(rhk, whp[jj], accC[jj]);
    }
    const bool valid = (l0 + lane) < NLINKS;
#pragma unroll 4
    for (int jj = 0; jj < 32; ++jj) {
      int j = hb + jj;
      float z    = g_lds[lane][j];
      float a    = g_lds[lane][128 + j];
      float hold = h_lds[lane][j];
      float hh = tanhf(a + accC[jj]);
      float hn = z * hold + (1.0f - z) * hh;
      if (valid) link_state[(l0 + lane) * DD + j] = hn;
    }
  }
}

// ============================================================================
// ATOMIC MODE (fallback, verified round 3) — used if ws_size is too small.
// ============================================================================

__global__ void init_kernel(const float* __restrict__ cap,
                            const float* __restrict__ traffic,
                            float* __restrict__ link_state,
                            float* __restrict__ path_state,
                            float* __restrict__ m) {
  int i = blockIdx.x * blockDim.x + threadIdx.x;
  if (i < NLINKS * DD) {
    link_state[i] = ((i & 63) == 0) ? cap[i >> 6] : 0.0f;
    m[i] = 0.0f;
  }
  if (i < NPATHS * DD) {
    path_state[i] = ((i & 63) == 0) ? traffic[i >> 6] : 0.0f;
  }
}

__global__ __launch_bounds__(384, 1) void path_gru_kernel(
    const float* __restrict__ link_state,
    float* __restrict__ path_state,
    float* __restrict__ m,
    const int* __restrict__ links,
    const float* __restrict__ Wx,
    const float* __restrict__ Wh,
    const float* __restrict__ bias) {
  __shared__ float h_lds[64][65];
  __shared__ float x_lds[64][65];
  __shared__ float r_lds[64][65];

  const int tid  = threadIdx.x;
  const int lane = tid & 63;
  const int w    = __builtin_amdgcn_readfirstlane(tid >> 6);
  const int p0   = blockIdx.x * 64;

  for (int idx = tid; idx < 64 * 16; idx += 384) {
    int p = idx >> 4, c = idx & 15;
    float4 v = make_float4(0.f, 0.f, 0.f, 0.f);
    if (p0 + p < NPATHS)
      v = reinterpret_cast<const float4*>(path_state)[(p0 + p) * 16 + c];
    h_lds[p][c * 4 + 0] = v.x; h_lds[p][c * 4 + 1] = v.y;
    h_lds[p][c * 4 + 2] = v.z; h_lds[p][c * 4 + 3] = v.w;
  }

  const int jb = (w < 4) ? (w * 32) : (128 + (w - 4) * 32);

  for (int t = 0; t < LSEQ; ++t) {
    __syncthreads();
    for (int idx = tid; idx < 64 * 16; idx += 384) {
      int p = idx >> 4, c = idx & 15;
      float4 v = make_float4(0.f, 0.f, 0.f, 0.f);
      if (p0 + p < NPATHS) {
        int li = links[(p0 + p) * LSEQ + t];
        v = reinterpret_cast<const float4*>(link_state)[li * 16 + c];
      }
      x_lds[p][c * 4 + 0] = v.x; x_lds[p][c * 4 + 1] = v.y;
      x_lds[p][c * 4 + 2] = v.z; x_lds[p][c * 4 + 3] = v.w;
    }
    __syncthreads();

    float accA[32], accB[32];
#pragma unroll
    for (int jj = 0; jj < 32; ++jj) { accA[jj] = bias[jb + jj]; accB[jj] = 0.0f; }
    if (w < 4) {
#pragma unroll 4
      for (int k = 0; k < DD; ++k) {
        float xk = x_lds[lane][k];
        float hk = h_lds[lane][k];
        const float* wxp = &Wx[k * GW + jb];
        const float* whp = &Wh[k * GW + jb];
#pragma unroll
        for (int jj = 0; jj < 32; ++jj) {
          accA[jj] = fmaf(xk, wxp[jj], accA[jj]);
          accB[jj] = fmaf(hk, whp[jj], accB[jj]);
        }
      }
    } else {
#pragma unroll 4
      for (int k = 0; k < DD; ++k) {
        float xk = x_lds[lane][k];
        const float* wxp = &Wx[k * GW + jb];
#pragma unroll
        for (int jj = 0; jj < 32; ++jj)
          accA[jj] = fmaf(xk, wxp[jj], accA[jj]);
      }
    }
    __syncthreads();

    if (w < 2) {
#pragma unroll
      for (int jj = 0; jj < 32; ++jj)
        x_lds[lane][jb + jj] = sigmoidf_(accA[jj] + accB[jj]);
    } else if (w < 4) {
#pragma unroll
      for (int jj = 0; jj < 32; ++jj) {
        int hj = jb - 64 + jj;
        float r = sigmoidf_(accA[jj] + accB[jj]);
        r_lds[lane][hj] = r * h_lds[lane][hj];
      }
    }
    __syncthreads();

    if (w >= 4) {
      const int hb = (w - 4) * 32;
      float accC[32];
#pragma unroll
      for (int jj = 0; jj < 32; ++jj) accC[jj] = 0.0f;
#pragma unroll 4
      for (int k = 0; k < DD; ++k) {
        float rhk = r_lds[lane][k];
        const float* whp = &Wh[k * GW + 128 + hb];
#pragma unroll
        for (int jj = 0; jj < 32; ++jj)
          accC[jj] = fmaf(rhk, whp[jj], accC[jj]);
      }
      const bool valid = (p0 + lane) < NPATHS;
      int li = 0;
      if (valid) li = links[(p0 + lane) * LSEQ + t];
#pragma unroll 4
      for (int jj = 0; jj < 32; ++jj) {
        int j = hb + jj;
        float z    = x_lds[lane][j];
        float hold = h_lds[lane][j];
        float hh = tanhf(accA[jj] + accC[jj]);
        float hn = z * hold + (1.0f - z) * hh;
        h_lds[lane][j] = hn;
        if (valid) {
          atomicAdd(&m[li * DD + j], hn);
          if (t == LSEQ - 1) path_state[(p0 + lane) * DD + j] = hn;
        }
      }
    }
  }
}

__global__ __launch_bounds__(384, 1) void link_gru_kernel(
    float* __restrict__ link_state,
    float* __restrict__ m,
    const float* __restrict__ Wx,
    const float* __restrict__ Wh,
    const float* __restrict__ bias) {
  __shared__ float h_lds[64][65];
  __shared__ float x_lds[64][65];
  __shared__ float r_lds[64][65];

  const int tid  = threadIdx.x;
  const int lane = tid & 63;
  const int w    = __builtin_amdgcn_readfirstlane(tid >> 6);
  const int l0   = blockIdx.x * 64;

  for (int idx = tid; idx < 64 * 16; idx += 384) {
    int p = idx >> 4, c = idx & 15;
    float4 hv = make_float4(0.f, 0.f, 0.f, 0.f);
    float4 xv = make_float4(0.f, 0.f, 0.f, 0.f);
    if (l0 + p < NLINKS) {
      hv = reinterpret_cast<const float4*>(link_state)[(l0 + p) * 16 + c];
      xv = reinterpret_cast<const float4*>(m)[(l0 + p) * 16 + c];
    }
    h_lds[p][c * 4 + 0] = hv.x; h_lds[p][c * 4 + 1] = hv.y;
    h_lds[p][c * 4 + 2] = hv.z; h_lds[p][c * 4 + 3] = hv.w;
    x_lds[p][c * 4 + 0] = xv.x; x_lds[p][c * 4 + 1] = xv.y;
    x_lds[p][c * 4 + 2] = xv.z; x_lds[p][c * 4 + 3] = xv.w;
  }
  __syncthreads();

  const int jb = (w < 4) ? (w * 32) : (128 + (w - 4) * 32);

  float accA[32], accB[32];
#pragma unroll
  for (int jj = 0; jj < 32; ++jj) { accA[jj] = bias[jb + jj]; accB[jj] = 0.0f; }
  if (w < 4) {
#pragma unroll 4
    for (int k = 0; k < DD; ++k) {
      float xk = x_lds[lane][k];
      float hk = h_lds[lane][k];
      const float* wxp = &Wx[k * GW + jb];
      const float* whp = &Wh[k * GW + jb];
#pragma unroll
      for (int jj = 0; jj < 32; ++jj) {
        accA[jj] = fmaf(xk, wxp[jj], accA[jj]);
        accB[jj] = fmaf(hk, whp[jj], accB[jj]);
      }
    }
  } else {
#pragma unroll 4
    for (int k = 0; k < DD; ++k) {
      float xk = x_lds[lane][k];
      const float* wxp = &Wx[k * GW + jb];
#pragma unroll
      for (int jj = 0; jj < 32; ++jj)
        accA[jj] = fmaf(xk, wxp[jj], accA[jj]);
    }
  }
  __syncthreads();

  if (w < 2) {
#pragma unroll
    for (int jj = 0; jj < 32; ++jj)
      x_lds[lane][jb + jj] = sigmoidf_(accA[jj] + accB[jj]);
  } else if (w < 4) {
#pragma unroll
    for (int jj = 0; jj < 32; ++jj) {
      int hj = jb - 64 + jj;
      float r = sigmoidf_(accA[jj] + accB[jj]);
      r_lds[lane][hj] = r * h_lds[lane][hj];
    }
  }
  __syncthreads();

  if (w >= 4) {
    const int hb = (w - 4) * 32;
    float accC[32];
#pragma unroll
    for (int jj = 0; jj < 32; ++jj) accC[jj] = 0.0f;
#pragma unroll 4
    for (int k = 0; k < DD; ++k) {
      float rhk = r_lds[lane][k];
      const float* whp = &Wh[k * GW + 128 + hb];
#pragma unroll
      for (int jj = 0; jj < 32; ++jj)
        accC[jj] = fmaf(rhk, whp[jj], accC[jj]);
    }
    const bool valid = (l0 + lane) < NLINKS;
#pragma unroll 4
    for (int jj = 0; jj < 32; ++jj) {
      int j = hb + jj;
      float z    = x_lds[lane][j];
      float hold = h_lds[lane][j];
      float hh = tanhf(accA[jj] + accC[jj]);
      float hn = z * hold + (1.0f - z) * hh;
      if (valid) {
        link_state[(l0 + lane) * DD + j] = hn;
        m[(l0 + lane) * DD + j] = 0.0f;
      }
    }
  }
}

// ---------------- readout MLP with exact-JAX dropout ----------------
// ps4 = float4 base of path_state rows; rs4 = row stride in float4 units.
__global__ __launch_bounds__(256, 1) void mlp_kernel(
    const float4* __restrict__ ps4, int rs4,
    const float* __restrict__ W1, const float* __restrict__ b1,
    const float* __restrict__ W2, const float* __restrict__ b2,
    const float* __restrict__ W3, const float* __restrict__ b3,
    float* __restrict__ out,
    uint32_t k1a, uint32_t k1b, uint32_t k2a, uint32_t k2b) {
  __shared__ float hbuf[64][256];

  const int tid  = threadIdx.x;
  const int lane = tid & 63;
  const int w    = __builtin_amdgcn_readfirstlane(tid >> 6);
  const int p0   = blockIdx.x * 64;
  const bool valid = (p0 + lane) < NPATHS;
  const int prow = valid ? (p0 + lane) : 0;

  float ps[DD];
  {
    const float4* src = ps4 + (size_t)prow * rs4;
#pragma unroll
    for (int c = 0; c < 16; ++c) {
      float4 v = src[c];
      ps[c * 4 + 0] = v.x; ps[c * 4 + 1] = v.y;
      ps[c * 4 + 2] = v.z; ps[c * 4 + 3] = v.w;
    }
  }

  const int cb = w * 64;
  const uint32_t base = (uint32_t)(p0 + lane) * 256u;
  float acc[64];

#pragma unroll
  for (int c = 0; c < 64; ++c) acc[c] = b1[cb + c];
#pragma unroll 2
  for (int k = 0; k < DD; ++k) {
    float pk = ps[k];
    const float* wp = &W1[k * 256 + cb];
#pragma unroll
    for (int c = 0; c < 64; ++c) acc[c] = fmaf(pk, wp[c], acc[c]);
  }
#pragma unroll 2
  for (int c = 0; c < 64; ++c) {
    int u = cb + c;
    float v = seluf_(acc[c]);
    bool keep = bern_keep(k1a, k1b, base + (uint32_t)u);
    hbuf[lane][(u + lane) & 255] = keep ? v * 2.0f : 0.0f;
  }
  __syncthreads();

#pragma unroll
  for (int c = 0; c < 64; ++c) acc[c] = b2[cb + c];
#pragma unroll 2
  for (int k = 0; k < 256; ++k) {
    float hk = hbuf[lane][(k + lane) & 255];
    const float* wp = &W2[k * 256 + cb];
#pragma unroll
    for (int c = 0; c < 64; ++c) acc[c] = fmaf(hk, wp[c], acc[c]);
  }
  __syncthreads();
#pragma unroll 2
  for (int c = 0; c < 64; ++c) {
    int u = cb + c;
    float v = seluf_(acc[c]);
    bool keep = bern_keep(k2a, k2b, base + (uint32_t)u);
    hbuf[lane][(u + lane) & 255] = keep ? v * 2.0f : 0.0f;
  }
  __syncthreads();

  if (w == 0) {
    float s = b3[0];
    for (int k = 0; k < 256; ++k)
      s = fmaf(hbuf[lane][(k + lane) & 255], W3[k], s);
    if (valid) out[p0 + lane] = s > 0.0f ? s : 0.0f;
  }
}

// ---------------- host ----------------
extern "C" void kernel_launch(void* const* d_in, const int* in_sizes, int n_in,
                              void* d_out, int out_size, void* d_ws, size_t ws_size,
                              hipStream_t stream) {
  const float* cap     = (const float*)d_in[0];
  const float* traffic = (const float*)d_in[1];
  const int*   links   = (const int*)d_in[2];
  const float* pWx = (const float*)d_in[5];
  const float* pWh = (const float*)d_in[6];
  const float* pb  = (const float*)d_in[7];
  const float* eWx = (const float*)d_in[8];
  const float* eWh = (const float*)d_in[9];
  const float* eb  = (const float*)d_in[10];
  const float* W1  = (const float*)d_in[11];
  const float* b1  = (const float*)d_in[12];
  const float* W2  = (const float*)d_in[13];
  const float* b2  = (const float*)d_in[14];
  const float* W3  = (const float*)d_in[15];
  const float* b3  = (const float*)d_in[16];
  float* out = (float*)d_out;

  uint32_t k1a, k1b, k2a, k2b;
  threefry2x32(0u, 1u, 0u, 0u, k1a, k1b);
  threefry2x32(0u, 1u, 0u, 1u, k2a, k2b);

  // gather-mode workspace requirement
  const size_t need = (size_t)NLINKS * DD * 4          // link_state
                    + (size_t)NPATHS * LSEQ * DD * 4   // seq_h
                    + (size_t)NLINKS * 4 * 3           // counts, row_start, cursor
                    + (size_t)NEDGE * 4;               // edges

  if (ws_size >= need) {
    float* link_state = (float*)d_ws;
    float* seq_h      = link_state + NLINKS * DD;
    int*   counts     = (int*)(seq_h + (size_t)NPATHS * LSEQ * DD);
    int*   row_start  = counts + NLINKS;
    int*   cursor     = row_start + NLINKS;
    int*   edges      = cursor + NLINKS;

    init_gather_kernel<<<(NLINKS * DD + 255) / 256, 256, 0, stream>>>(
        cap, traffic, link_state, seq_h, counts);
    csr_hist_kernel<<<(NEDGE + 255) / 256, 256, 0, stream>>>(links, counts);
    csr_scan_kernel<<<1, 1024, 0, stream>>>(counts, row_start, cursor);
    csr_fill_kernel<<<(NEDGE + 255) / 256, 256, 0, stream>>>(links, cursor, edges);

    for (int it = 0; it < TITER; ++it) {
      path_gru_gather_kernel<<<NB, 384, 0, stream>>>(link_state, seq_h, links,
                                                     pWx, pWh, pb);
      link_gru_gather_kernel<<<NB, 384, 0, stream>>>(link_state, seq_h,
                                                     row_start, cursor, edges,
                                                     eWx, eWh, eb);
    }
    // path_state rows live at seq_h[(p*8+7)*64]
    mlp_kernel<<<NB, 256, 0, stream>>>(
        (const float4*)seq_h + 7 * 16, LSEQ * 16,
        W1, b1, W2, b2, W3, b3, out, k1a, k1b, k2a, k2b);
  } else {
    float* link_state = (float*)d_ws;
    float* path_state = link_state + NLINKS * DD;
    float* m          = path_state + NPATHS * DD;

    init_kernel<<<(NLINKS * DD + 255) / 256, 256, 0, stream>>>(
        cap, traffic, link_state, path_state, m);
    for (int it = 0; it < TITER; ++it) {
      path_gru_kernel<<<NB, 384, 0, stream>>>(link_state, path_state, m, links,
                                              pWx, pWh, pb);
      link_gru_kernel<<<NB, 384, 0, stream>>>(link_state, m, eWx, eWh, eb);
    }
    mlp_kernel<<<NB, 256, 0, stream>>>(
        (const float4*)path_state, 16,
        W1, b1, W2, b2, W3, b3, out, k1a, k1b, k2a, k2b);
  }
}

// Round 5
// 2873.798 us; speedup vs baseline: 2.0231x; 1.7363x over previous
//
#include <hip/hip_runtime.h>
#include <cstdint>

// Problem constants (fixed by setup_inputs()).
#define NLINKS 20000
#define NPATHS 20000
#define LSEQ   8
#define TITER  8
#define DD     64
#define GW     192          // 3*DD gate width
#define NEDGE  (NPATHS * LSEQ)        // 160000
#define NB     ((NPATHS + 63) / 64)   // 313 blocks of 64 rows

// ---------------- Threefry-2x32 (exact JAX semantics) ----------------
__host__ __device__ static inline uint32_t rotl32(uint32_t x, unsigned r) {
  return (x << r) | (x >> (32u - r));
}

__host__ __device__ static inline void threefry2x32(uint32_t k0, uint32_t k1,
                                                    uint32_t c0, uint32_t c1,
                                                    uint32_t& o0, uint32_t& o1) {
  uint32_t ks0 = k0, ks1 = k1, ks2 = k0 ^ k1 ^ 0x1BD11BDAu;
  uint32_t x0 = c0 + ks0, x1 = c1 + ks1;
#define TF_R(r) { x0 += x1; x1 = rotl32(x1, r); x1 ^= x0; }
  TF_R(13) TF_R(15) TF_R(26) TF_R(6)  x0 += ks1; x1 += ks2 + 1u;
  TF_R(17) TF_R(29) TF_R(16) TF_R(24) x0 += ks2; x1 += ks0 + 2u;
  TF_R(13) TF_R(15) TF_R(26) TF_R(6)  x0 += ks0; x1 += ks1 + 3u;
  TF_R(17) TF_R(29) TF_R(16) TF_R(24) x0 += ks1; x1 += ks2 + 4u;
  TF_R(13) TF_R(15) TF_R(26) TF_R(6)  x0 += ks2; x1 += ks0 + 5u;
#undef TF_R
  o0 = x0; o1 = x1;
}

// bernoulli(key, 0.5, (20000,256)), flattened element j.
// jax_threefry_partitionable=True: counter (0, j), bits = o0 ^ o1.
__device__ static inline bool bern_keep(uint32_t key0, uint32_t key1, uint32_t j) {
  uint32_t o0, o1;
  threefry2x32(key0, key1, 0u, j, o0, o1);
  uint32_t bits = o0 ^ o1;
  float u = __uint_as_float((bits >> 9) | 0x3f800000u) - 1.0f;
  return u < 0.5f;
}

__device__ static inline float sigmoidf_(float x) { return 1.0f / (1.0f + expf(-x)); }
__device__ static inline float seluf_(float x) {
  const float sc = 1.0507009873554805f;
  const float al = 1.6732632423543772f;
  return x > 0.0f ? sc * x : sc * al * expm1f(x);
}

// ---------------- init + CSR build ----------------
__global__ void init_gather_kernel(const float* __restrict__ cap,
                                   const float* __restrict__ traffic,
                                   float* __restrict__ link_state,
                                   float* __restrict__ seq_h,
                                   int* __restrict__ counts) {
  int i = blockIdx.x * blockDim.x + threadIdx.x;
  if (i < NLINKS * DD)
    link_state[i] = ((i & 63) == 0) ? cap[i >> 6] : 0.0f;
  if (i < NPATHS * DD) {
    int p = i >> 6, j = i & 63;
    seq_h[(p * LSEQ + (LSEQ - 1)) * DD + j] = (j == 0) ? traffic[p] : 0.0f;
  }
  if (i < NLINKS) counts[i] = 0;
}

__global__ void csr_hist_kernel(const int* __restrict__ links,
                                int* __restrict__ counts) {
  int e = blockIdx.x * blockDim.x + threadIdx.x;
  if (e < NEDGE) atomicAdd(&counts[links[e]], 1);
}

__global__ __launch_bounds__(1024, 1) void csr_scan_kernel(
    const int* __restrict__ counts,
    int* __restrict__ row_start,
    int* __restrict__ cursor) {
  __shared__ int sc[1024];
  const int i = threadIdx.x;
  const int base = i * 20;
  int s = 0;
  for (int j = 0; j < 20; ++j) {
    int r = base + j;
    if (r < NLINKS) s += counts[r];
  }
  sc[i] = s;
  __syncthreads();
  for (int off = 1; off < 1024; off <<= 1) {
    int v = (i >= off) ? sc[i - off] : 0;
    __syncthreads();
    sc[i] += v;
    __syncthreads();
  }
  int run = sc[i] - s;
  for (int j = 0; j < 20; ++j) {
    int r = base + j;
    if (r < NLINKS) {
      row_start[r] = run;
      cursor[r] = run;
      run += counts[r];
    }
  }
}

__global__ void csr_fill_kernel(const int* __restrict__ links,
                                int* __restrict__ cursor,
                                int* __restrict__ edges) {
  int e = blockIdx.x * blockDim.x + threadIdx.x;
  if (e < NEDGE) {
    int l = links[e];
    int pos = atomicAdd(&cursor[l], 1);
    edges[pos] = e;
  }
}

// ============================================================================
// path GRU v5: LDS-resident weights, 8 waves, balanced octet schedule.
// Reference GRU (Python precedence): hh = tanh(xh + (r*h) @ Wh[:,2D:]).
// Wave w: phase1 -> AB cols [16w,16w+16) (z if <64 else rh), cand-A cols
// [128+8w,128+8w+8); phase2 -> accC + h-update for h cols [8w,8w+8).
// ============================================================================
__global__ __launch_bounds__(512, 1) void path_gru_kernel(
    const float* __restrict__ link_state,
    float* __restrict__ seq_h,
    const int* __restrict__ links,
    const float* __restrict__ Wx,
    const float* __restrict__ Wh,
    const float* __restrict__ bias) {
  __shared__ float wx_s[DD * GW];   // 48 KB
  __shared__ float wh_s[DD * GW];   // 48 KB
  __shared__ float h_s[64][65];
  __shared__ float x_s[64][65];     // holds x in p1; z after BAR2
  __shared__ float r_s[64][65];     // rh

  const int tid  = threadIdx.x;
  const int lane = tid & 63;
  const int w    = __builtin_amdgcn_readfirstlane(tid >> 6);
  const int p0   = blockIdx.x * 64;

  // stage weights (one-time): 6144 float4 / 512 thr = 12 each
  for (int i = tid; i < (DD * GW) / 4; i += 512) {
    reinterpret_cast<float4*>(wx_s)[i] = reinterpret_cast<const float4*>(Wx)[i];
    reinterpret_cast<float4*>(wh_s)[i] = reinterpret_cast<const float4*>(Wh)[i];
  }
  // load carried h (seq row 7)
  for (int i = tid; i < 1024; i += 512) {
    int p = i >> 4, c = i & 15;
    int pr = min(p0 + p, NPATHS - 1);
    float4 v = reinterpret_cast<const float4*>(seq_h)[(pr * LSEQ + 7) * 16 + c];
    h_s[p][c * 4 + 0] = v.x; h_s[p][c * 4 + 1] = v.y;
    h_s[p][c * 4 + 2] = v.z; h_s[p][c * 4 + 3] = v.w;
  }

  const int abc0 = w * 16;        // AB col base
  const int cc0  = 128 + w * 8;   // cand col base
  const int hc0  = w * 8;         // update col base

  float bab[16], bcc[8];
#pragma unroll
  for (int jj = 0; jj < 16; ++jj) bab[jj] = bias[abc0 + jj];
#pragma unroll
  for (int jj = 0; jj < 8;  ++jj) bcc[jj] = bias[cc0 + jj];

  // x(0) prefetch: 1024 f4 slots / 512 thr = 2 each
  float4 pf[2];
#pragma unroll
  for (int s = 0; s < 2; ++s) {
    int slot = tid + 512 * s;
    int p = slot >> 4, c = slot & 15;
    int pr = min(p0 + p, NPATHS - 1);
    int li = links[pr * LSEQ + 0];
    pf[s] = reinterpret_cast<const float4*>(link_state)[li * 16 + c];
  }
  __syncthreads();   // weights + h ready; (x_s free)

  for (int t = 0; t < LSEQ; ++t) {
    // (A) write x(t) from prefetch regs
#pragma unroll
    for (int s = 0; s < 2; ++s) {
      int slot = tid + 512 * s;
      int p = slot >> 4, c = slot & 15;
      x_s[p][c * 4 + 0] = pf[s].x; x_s[p][c * 4 + 1] = pf[s].y;
      x_s[p][c * 4 + 2] = pf[s].z; x_s[p][c * 4 + 3] = pf[s].w;
    }
    __syncthreads();  // BAR1: x ready

    // issue x(t+1) gather (latency hides under phase 1)
    if (t < LSEQ - 1) {
#pragma unroll
      for (int s = 0; s < 2; ++s) {
        int slot = tid + 512 * s;
        int p = slot >> 4, c = slot & 15;
        int pr = min(p0 + p, NPATHS - 1);
        int li = links[pr * LSEQ + t + 1];
        pf[s] = reinterpret_cast<const float4*>(link_state)[li * 16 + c];
      }
    }
    // store out(t-1) = current h (stable during p1)
    if (t > 0) {
#pragma unroll
      for (int s = 0; s < 2; ++s) {
        int slot = tid + 512 * s;
        int p = slot >> 4, c = slot & 15;
        if (p0 + p < NPATHS) {
          float4 v = make_float4(h_s[p][c * 4 + 0], h_s[p][c * 4 + 1],
                                 h_s[p][c * 4 + 2], h_s[p][c * 4 + 3]);
          reinterpret_cast<float4*>(seq_h)[((p0 + p) * LSEQ + (t - 1)) * 16 + c] = v;
        }
      }
    }

    // phase 1
    float aA[16], aB[16], cA[8];
#pragma unroll
    for (int jj = 0; jj < 16; ++jj) { aA[jj] = bab[jj]; aB[jj] = 0.0f; }
#pragma unroll
    for (int jj = 0; jj < 8; ++jj) cA[jj] = bcc[jj];
#pragma unroll 4
    for (int k = 0; k < DD; ++k) {
      float xk = x_s[lane][k];
      float hk = h_s[lane][k];
      const float* wxp = &wx_s[k * GW + abc0];
      const float* whp = &wh_s[k * GW + abc0];
      const float* wxc = &wx_s[k * GW + cc0];
#pragma unroll
      for (int jj = 0; jj < 16; ++jj) {
        aA[jj] = fmaf(xk, wxp[jj], aA[jj]);
        aB[jj] = fmaf(hk, whp[jj], aB[jj]);
      }
#pragma unroll
      for (int jj = 0; jj < 8; ++jj)
        cA[jj] = fmaf(xk, wxc[jj], cA[jj]);
    }
    __syncthreads();  // BAR2: all x/h reads done

    // gate writes
    if (abc0 < 64) {
#pragma unroll
      for (int jj = 0; jj < 16; ++jj)
        x_s[lane][abc0 + jj] = sigmoidf_(aA[jj] + aB[jj]);      // z
    } else {
#pragma unroll
      for (int jj = 0; jj < 16; ++jj) {
        int hj = abc0 - 64 + jj;
        float r = sigmoidf_(aA[jj] + aB[jj]);
        r_s[lane][hj] = r * h_s[lane][hj];                       // rh
      }
    }
    __syncthreads();  // BAR3: gates ready

    // phase 2: accC + update
    float aC[8];
#pragma unroll
    for (int jj = 0; jj < 8; ++jj) aC[jj] = 0.0f;
#pragma unroll 4
    for (int k = 0; k < DD; ++k) {
      float rhk = r_s[lane][k];
      const float* whc = &wh_s[k * GW + cc0];
#pragma unroll
      for (int jj = 0; jj < 8; ++jj)
        aC[jj] = fmaf(rhk, whc[jj], aC[jj]);
    }
#pragma unroll
    for (int jj = 0; jj < 8; ++jj) {
      int j = hc0 + jj;
      float z    = x_s[lane][j];
      float hold = h_s[lane][j];
      float hh = tanhf(cA[jj] + aC[jj]);
      h_s[lane][j] = z * hold + (1.0f - z) * hh;
    }
    __syncthreads();  // BAR0: h updated, z consumed, x_s free
  }

  // final store: out(7) (also the carried state) -> seq row 7
#pragma unroll
  for (int s = 0; s < 2; ++s) {
    int slot = tid + 512 * s;
    int p = slot >> 4, c = slot & 15;
    if (p0 + p < NPATHS) {
      float4 v = make_float4(h_s[p][c * 4 + 0], h_s[p][c * 4 + 1],
                             h_s[p][c * 4 + 2], h_s[p][c * 4 + 3]);
      reinterpret_cast<float4*>(seq_h)[((p0 + p) * LSEQ + 7) * 16 + c] = v;
    }
  }
}

// ============================================================================
// link GRU v5: same schedule; x = CSR-gathered sum of seq_h rows.
// ============================================================================
__global__ __launch_bounds__(512, 1) void link_gru_kernel(
    float* __restrict__ link_state,
    const float* __restrict__ seq_h,
    const int* __restrict__ row_start,
    const int* __restrict__ row_end,
    const int* __restrict__ edges,
    const float* __restrict__ Wx,
    const float* __restrict__ Wh,
    const float* __restrict__ bias) {
  __shared__ float wx_s[DD * GW];
  __shared__ float wh_s[DD * GW];
  __shared__ float h_s[64][65];
  __shared__ float x_s[64][65];
  __shared__ float r_s[64][65];

  const int tid  = threadIdx.x;
  const int lane = tid & 63;
  const int w    = __builtin_amdgcn_readfirstlane(tid >> 6);
  const int l0   = blockIdx.x * 64;

  for (int i = tid; i < (DD * GW) / 4; i += 512) {
    reinterpret_cast<float4*>(wx_s)[i] = reinterpret_cast<const float4*>(Wx)[i];
    reinterpret_cast<float4*>(wh_s)[i] = reinterpret_cast<const float4*>(Wh)[i];
  }
  for (int i = tid; i < 1024; i += 512) {
    int p = i >> 4, c = i & 15;
    float4 hv = make_float4(0.f, 0.f, 0.f, 0.f);
    float4 xv = make_float4(0.f, 0.f, 0.f, 0.f);
    if (l0 + p < NLINKS) {
      hv = reinterpret_cast<const float4*>(link_state)[(l0 + p) * 16 + c];
      int rs = row_start[l0 + p], re = row_end[l0 + p];
      for (int ii = rs; ii < re; ++ii) {
        int e = edges[ii];
        float4 v = reinterpret_cast<const float4*>(seq_h)[e * 16 + c];
        xv.x += v.x; xv.y += v.y; xv.z += v.z; xv.w += v.w;
      }
    }
    h_s[p][c * 4 + 0] = hv.x; h_s[p][c * 4 + 1] = hv.y;
    h_s[p][c * 4 + 2] = hv.z; h_s[p][c * 4 + 3] = hv.w;
    x_s[p][c * 4 + 0] = xv.x; x_s[p][c * 4 + 1] = xv.y;
    x_s[p][c * 4 + 2] = xv.z; x_s[p][c * 4 + 3] = xv.w;
  }

  const int abc0 = w * 16;
  const int cc0  = 128 + w * 8;
  const int hc0  = w * 8;

  float bab[16], bcc[8];
#pragma unroll
  for (int jj = 0; jj < 16; ++jj) bab[jj] = bias[abc0 + jj];
#pragma unroll
  for (int jj = 0; jj < 8;  ++jj) bcc[jj] = bias[cc0 + jj];

  __syncthreads();

  float aA[16], aB[16], cA[8];
#pragma unroll
  for (int jj = 0; jj < 16; ++jj) { aA[jj] = bab[jj]; aB[jj] = 0.0f; }
#pragma unroll
  for (int jj = 0; jj < 8; ++jj) cA[jj] = bcc[jj];
#pragma unroll 4
  for (int k = 0; k < DD; ++k) {
    float xk = x_s[lane][k];
    float hk = h_s[lane][k];
    const float* wxp = &wx_s[k * GW + abc0];
    const float* whp = &wh_s[k * GW + abc0];
    const float* wxc = &wx_s[k * GW + cc0];
#pragma unroll
    for (int jj = 0; jj < 16; ++jj) {
      aA[jj] = fmaf(xk, wxp[jj], aA[jj]);
      aB[jj] = fmaf(hk, whp[jj], aB[jj]);
    }
#pragma unroll
    for (int jj = 0; jj < 8; ++jj)
      cA[jj] = fmaf(xk, wxc[jj], cA[jj]);
  }
  __syncthreads();

  if (abc0 < 64) {
#pragma unroll
    for (int jj = 0; jj < 16; ++jj)
      x_s[lane][abc0 + jj] = sigmoidf_(aA[jj] + aB[jj]);
  } else {
#pragma unroll
    for (int jj = 0; jj < 16; ++jj) {
      int hj = abc0 - 64 + jj;
      float r = sigmoidf_(aA[jj] + aB[jj]);
      r_s[lane][hj] = r * h_s[lane][hj];
    }
  }
  __syncthreads();

  float aC[8];
#pragma unroll
  for (int jj = 0; jj < 8; ++jj) aC[jj] = 0.0f;
#pragma unroll 4
  for (int k = 0; k < DD; ++k) {
    float rhk = r_s[lane][k];
    const float* whc = &wh_s[k * GW + cc0];
#pragma unroll
    for (int jj = 0; jj < 8; ++jj)
      aC[jj] = fmaf(rhk, whc[jj], aC[jj]);
  }
  const bool valid = (l0 + lane) < NLINKS;
#pragma unroll
  for (int jj = 0; jj < 8; ++jj) {
    int j = hc0 + jj;
    float z    = x_s[lane][j];
    float hold = h_s[lane][j];
    float hh = tanhf(cA[jj] + aC[jj]);
    float hn = z * hold + (1.0f - z) * hh;
    if (valid) link_state[(l0 + lane) * DD + j] = hn;
  }
}

// ---------------- readout MLP with exact-JAX dropout ----------------
__global__ __launch_bounds__(256, 1) void mlp_kernel(
    const float4* __restrict__ ps4, int rs4,
    const float* __restrict__ W1, const float* __restrict__ b1,
    const float* __restrict__ W2, const float* __restrict__ b2,
    const float* __restrict__ W3, const float* __restrict__ b3,
    float* __restrict__ out,
    uint32_t k1a, uint32_t k1b, uint32_t k2a, uint32_t k2b) {
  __shared__ float hbuf[64][256];

  const int tid  = threadIdx.x;
  const int lane = tid & 63;
  const int w    = __builtin_amdgcn_readfirstlane(tid >> 6);
  const int p0   = blockIdx.x * 64;
  const bool valid = (p0 + lane) < NPATHS;
  const int prow = valid ? (p0 + lane) : 0;

  float ps[DD];
  {
    const float4* src = ps4 + (size_t)prow * rs4;
#pragma unroll
    for (int c = 0; c < 16; ++c) {
      float4 v = src[c];
      ps[c * 4 + 0] = v.x; ps[c * 4 + 1] = v.y;
      ps[c * 4 + 2] = v.z; ps[c * 4 + 3] = v.w;
    }
  }

  const int cb = w * 64;
  const uint32_t base = (uint32_t)(p0 + lane) * 256u;
  float acc[64];

#pragma unroll
  for (int c = 0; c < 64; ++c) acc[c] = b1[cb + c];
#pragma unroll 2
  for (int k = 0; k < DD; ++k) {
    float pk = ps[k];
    const float* wp = &W1[k * 256 + cb];
#pragma unroll
    for (int c = 0; c < 64; ++c) acc[c] = fmaf(pk, wp[c], acc[c]);
  }
#pragma unroll 2
  for (int c = 0; c < 64; ++c) {
    int u = cb + c;
    float v = seluf_(acc[c]);
    bool keep = bern_keep(k1a, k1b, base + (uint32_t)u);
    hbuf[lane][(u + lane) & 255] = keep ? v * 2.0f : 0.0f;
  }
  __syncthreads();

#pragma unroll
  for (int c = 0; c < 64; ++c) acc[c] = b2[cb + c];
#pragma unroll 2
  for (int k = 0; k < 256; ++k) {
    float hk = hbuf[lane][(k + lane) & 255];
    const float* wp = &W2[k * 256 + cb];
#pragma unroll
    for (int c = 0; c < 64; ++c) acc[c] = fmaf(hk, wp[c], acc[c]);
  }
  __syncthreads();
#pragma unroll 2
  for (int c = 0; c < 64; ++c) {
    int u = cb + c;
    float v = seluf_(acc[c]);
    bool keep = bern_keep(k2a, k2b, base + (uint32_t)u);
    hbuf[lane][(u + lane) & 255] = keep ? v * 2.0f : 0.0f;
  }
  __syncthreads();

  if (w == 0) {
    float s = b3[0];
    for (int k = 0; k < 256; ++k)
      s = fmaf(hbuf[lane][(k + lane) & 255], W3[k], s);
    if (valid) out[p0 + lane] = s > 0.0f ? s : 0.0f;
  }
}

// ---------------- host ----------------
extern "C" void kernel_launch(void* const* d_in, const int* in_sizes, int n_in,
                              void* d_out, int out_size, void* d_ws, size_t ws_size,
                              hipStream_t stream) {
  const float* cap     = (const float*)d_in[0];
  const float* traffic = (const float*)d_in[1];
  const int*   links   = (const int*)d_in[2];
  const float* pWx = (const float*)d_in[5];
  const float* pWh = (const float*)d_in[6];
  const float* pb  = (const float*)d_in[7];
  const float* eWx = (const float*)d_in[8];
  const float* eWh = (const float*)d_in[9];
  const float* eb  = (const float*)d_in[10];
  const float* W1  = (const float*)d_in[11];
  const float* b1  = (const float*)d_in[12];
  const float* W2  = (const float*)d_in[13];
  const float* b2  = (const float*)d_in[14];
  const float* W3  = (const float*)d_in[15];
  const float* b3  = (const float*)d_in[16];
  float* out = (float*)d_out;

  uint32_t k1a, k1b, k2a, k2b;
  threefry2x32(0u, 1u, 0u, 0u, k1a, k1b);
  threefry2x32(0u, 1u, 0u, 1u, k2a, k2b);

  float* link_state = (float*)d_ws;
  float* seq_h      = link_state + NLINKS * DD;
  int*   counts     = (int*)(seq_h + (size_t)NPATHS * LSEQ * DD);
  int*   row_start  = counts + NLINKS;
  int*   cursor     = row_start + NLINKS;
  int*   edges      = cursor + NLINKS;

  init_gather_kernel<<<(NLINKS * DD + 255) / 256, 256, 0, stream>>>(
      cap, traffic, link_state, seq_h, counts);
  csr_hist_kernel<<<(NEDGE + 255) / 256, 256, 0, stream>>>(links, counts);
  csr_scan_kernel<<<1, 1024, 0, stream>>>(counts, row_start, cursor);
  csr_fill_kernel<<<(NEDGE + 255) / 256, 256, 0, stream>>>(links, cursor, edges);

  for (int it = 0; it < TITER; ++it) {
    path_gru_kernel<<<NB, 512, 0, stream>>>(link_state, seq_h, links,
                                            pWx, pWh, pb);
    link_gru_kernel<<<NB, 512, 0, stream>>>(link_state, seq_h,
                                            row_start, cursor, edges,
                                            eWx, eWh, eb);
  }
  mlp_kernel<<<NB, 256, 0, stream>>>(
      (const float4*)seq_h + 7 * 16, LSEQ * 16,
      W1, b1, W2, b2, W3, b3, out, k1a, k1b, k2a, k2b);
}

// Round 6
// 2359.307 us; speedup vs baseline: 2.4643x; 1.2181x over previous
//
#include <hip/hip_runtime.h>
#include <cstdint>

// Problem constants (fixed by setup_inputs()).
#define NLINKS 20000
#define NPATHS 20000
#define LSEQ   8
#define TITER  8
#define DD     64
#define GW     192          // 3*DD gate width
#define NEDGE  (NPATHS * LSEQ)        // 160000
#define NB     ((NPATHS + 63) / 64)   // 313 blocks of 64 rows

// ---------------- Threefry-2x32 (exact JAX semantics) ----------------
__host__ __device__ static inline uint32_t rotl32(uint32_t x, unsigned r) {
  return (x << r) | (x >> (32u - r));
}

__host__ __device__ static inline void threefry2x32(uint32_t k0, uint32_t k1,
                                                    uint32_t c0, uint32_t c1,
                                                    uint32_t& o0, uint32_t& o1) {
  uint32_t ks0 = k0, ks1 = k1, ks2 = k0 ^ k1 ^ 0x1BD11BDAu;
  uint32_t x0 = c0 + ks0, x1 = c1 + ks1;
#define TF_R(r) { x0 += x1; x1 = rotl32(x1, r); x1 ^= x0; }
  TF_R(13) TF_R(15) TF_R(26) TF_R(6)  x0 += ks1; x1 += ks2 + 1u;
  TF_R(17) TF_R(29) TF_R(16) TF_R(24) x0 += ks2; x1 += ks0 + 2u;
  TF_R(13) TF_R(15) TF_R(26) TF_R(6)  x0 += ks0; x1 += ks1 + 3u;
  TF_R(17) TF_R(29) TF_R(16) TF_R(24) x0 += ks1; x1 += ks2 + 4u;
  TF_R(13) TF_R(15) TF_R(26) TF_R(6)  x0 += ks2; x1 += ks0 + 5u;
#undef TF_R
  o0 = x0; o1 = x1;
}

// bernoulli(key, 0.5, (20000,256)), flattened element j.
// jax_threefry_partitionable=True: counter (0, j), bits = o0 ^ o1.
__device__ static inline bool bern_keep(uint32_t key0, uint32_t key1, uint32_t j) {
  uint32_t o0, o1;
  threefry2x32(key0, key1, 0u, j, o0, o1);
  uint32_t bits = o0 ^ o1;
  float u = __uint_as_float((bits >> 9) | 0x3f800000u) - 1.0f;
  return u < 0.5f;
}

__device__ static inline float sigmoidf_(float x) { return 1.0f / (1.0f + expf(-x)); }
__device__ static inline float seluf_(float x) {
  const float sc = 1.0507009873554805f;
  const float al = 1.6732632423543772f;
  return x > 0.0f ? sc * x : sc * al * expm1f(x);
}

// ---------------- init + CSR build ----------------
__global__ void init_gather_kernel(const float* __restrict__ cap,
                                   const float* __restrict__ traffic,
                                   float* __restrict__ link_state,
                                   float* __restrict__ seq_h,
                                   int* __restrict__ counts) {
  int i = blockIdx.x * blockDim.x + threadIdx.x;
  if (i < NLINKS * DD)
    link_state[i] = ((i & 63) == 0) ? cap[i >> 6] : 0.0f;
  if (i < NPATHS * DD) {
    int p = i >> 6, j = i & 63;
    seq_h[(p * LSEQ + (LSEQ - 1)) * DD + j] = (j == 0) ? traffic[p] : 0.0f;
  }
  if (i < NLINKS) counts[i] = 0;
}

__global__ void csr_hist_kernel(const int* __restrict__ links,
                                int* __restrict__ counts) {
  int e = blockIdx.x * blockDim.x + threadIdx.x;
  if (e < NEDGE) atomicAdd(&counts[links[e]], 1);
}

__global__ __launch_bounds__(1024, 1) void csr_scan_kernel(
    const int* __restrict__ counts,
    int* __restrict__ row_start,
    int* __restrict__ cursor) {
  __shared__ int sc[1024];
  const int i = threadIdx.x;
  const int base = i * 20;
  int s = 0;
  for (int j = 0; j < 20; ++j) {
    int r = base + j;
    if (r < NLINKS) s += counts[r];
  }
  sc[i] = s;
  __syncthreads();
  for (int off = 1; off < 1024; off <<= 1) {
    int v = (i >= off) ? sc[i - off] : 0;
    __syncthreads();
    sc[i] += v;
    __syncthreads();
  }
  int run = sc[i] - s;
  for (int j = 0; j < 20; ++j) {
    int r = base + j;
    if (r < NLINKS) {
      row_start[r] = run;
      cursor[r] = run;
      run += counts[r];
    }
  }
}

__global__ void csr_fill_kernel(const int* __restrict__ links,
                                int* __restrict__ cursor,
                                int* __restrict__ edges) {
  int e = blockIdx.x * blockDim.x + threadIdx.x;
  if (e < NEDGE) {
    int l = links[e];
    int pos = atomicAdd(&cursor[l], 1);
    edges[pos] = e;
  }
}

// ============================================================================
// gx kernel: gx[l][0..192) = link_state[l] @ pWx + pb   (per message-pass iter)
// block = 512 thr / 64 links; wave w owns cols [24w, 24w+24).
// LDS = Wx 48KB + ls tile 16.25KB -> 2 blocks/CU.
// ============================================================================
__global__ __launch_bounds__(512, 2) void gx_kernel(
    const float* __restrict__ link_state,
    const float* __restrict__ Wx,
    const float* __restrict__ bias,
    float* __restrict__ gx) {
  __shared__ float wx_s[DD * GW];
  __shared__ float ls_s[64][65];

  const int tid  = threadIdx.x;
  const int lane = tid & 63;
  const int w    = __builtin_amdgcn_readfirstlane(tid >> 6);
  const int l0   = blockIdx.x * 64;

  for (int i = tid; i < (DD * GW) / 4; i += 512)
    reinterpret_cast<float4*>(wx_s)[i] = reinterpret_cast<const float4*>(Wx)[i];
  for (int i = tid; i < 1024; i += 512) {
    int p = i >> 4, c = i & 15;
    int lr = min(l0 + p, NLINKS - 1);
    float4 v = reinterpret_cast<const float4*>(link_state)[lr * 16 + c];
    ls_s[p][c * 4 + 0] = v.x; ls_s[p][c * 4 + 1] = v.y;
    ls_s[p][c * 4 + 2] = v.z; ls_s[p][c * 4 + 3] = v.w;
  }

  const int c0 = w * 24;
  float acc[24];
#pragma unroll
  for (int jj = 0; jj < 24; ++jj) acc[jj] = bias[c0 + jj];
  __syncthreads();

#pragma unroll 4
  for (int k = 0; k < DD; ++k) {
    float xk = ls_s[lane][k];
    const float* wxp = &wx_s[k * GW + c0];
#pragma unroll
    for (int jj = 0; jj < 24; ++jj)
      acc[jj] = fmaf(xk, wxp[jj], acc[jj]);
  }

  if (l0 + lane < NLINKS) {
    float* dst = &gx[(size_t)(l0 + lane) * GW + c0];
#pragma unroll
    for (int s = 0; s < 6; ++s) {
      float4 v = make_float4(acc[s * 4 + 0], acc[s * 4 + 1],
                             acc[s * 4 + 2], acc[s * 4 + 3]);
      reinterpret_cast<float4*>(dst)[s] = v;
    }
  }
}

// ============================================================================
// path GRU v6: x@Wx+b comes pre-gathered from gx (per-lane register gathers).
// Recurrent work only: aB = h@Wh[:, :128] (16 cols/wave), phase2 rh@Wh3
// (8 cols/wave). 2 barriers/step. LDS = Wh 48KB + h/z/r tiles = 96.75KB.
// Reference GRU (Python precedence): hh = tanh(xh + (r*h) @ Wh[:,2D:]).
// ============================================================================
__global__ __launch_bounds__(512, 1) void path_gru_v6_kernel(
    const float* __restrict__ gx,
    float* __restrict__ seq_h,
    const int* __restrict__ links,
    const float* __restrict__ Wh) {
  __shared__ float wh_s[DD * GW];   // 48 KB
  __shared__ float h_s[64][65];
  __shared__ float z_s[64][65];
  __shared__ float r_s[64][65];     // rh

  const int tid  = threadIdx.x;
  const int lane = tid & 63;
  const int w    = __builtin_amdgcn_readfirstlane(tid >> 6);
  const int p0   = blockIdx.x * 64;

  for (int i = tid; i < (DD * GW) / 4; i += 512)
    reinterpret_cast<float4*>(wh_s)[i] = reinterpret_cast<const float4*>(Wh)[i];
  for (int i = tid; i < 1024; i += 512) {
    int p = i >> 4, c = i & 15;
    int pr = min(p0 + p, NPATHS - 1);
    float4 v = reinterpret_cast<const float4*>(seq_h)[(pr * LSEQ + 7) * 16 + c];
    h_s[p][c * 4 + 0] = v.x; h_s[p][c * 4 + 1] = v.y;
    h_s[p][c * 4 + 2] = v.z; h_s[p][c * 4 + 3] = v.w;
  }

  const int abc0 = w * 16;        // gate col base (z if <64 else r)
  const int cc0  = 128 + w * 8;   // cand col base
  const int hc0  = w * 8;         // phase-2 h col base
  const int prow = min(p0 + lane, NPATHS - 1);

  // gathers for t=0
  int li_cur = links[prow * LSEQ + 0];
  float4 gz4[4], gc4[2];
  {
    const float4* g = reinterpret_cast<const float4*>(gx) + (size_t)li_cur * (GW / 4);
#pragma unroll
    for (int s = 0; s < 4; ++s) gz4[s] = g[abc0 / 4 + s];
#pragma unroll
    for (int s = 0; s < 2; ++s) gc4[s] = g[cc0 / 4 + s];
  }
  __syncthreads();   // weights + h ready

  for (int t = 0; t < LSEQ; ++t) {
    // prefetch next step's link index early (consumed at end of phase 2)
    int li_next = (t < LSEQ - 1) ? links[prow * LSEQ + t + 1] : 0;

    // store out(t-1) = current h (h_s stable during phase 1), coalesced
    if (t > 0) {
#pragma unroll
      for (int s = 0; s < 2; ++s) {
        int slot = tid + 512 * s;
        int p = slot >> 4, c = slot & 15;
        if (p0 + p < NPATHS) {
          float4 v = make_float4(h_s[p][c * 4 + 0], h_s[p][c * 4 + 1],
                                 h_s[p][c * 4 + 2], h_s[p][c * 4 + 3]);
          reinterpret_cast<float4*>(seq_h)[((p0 + p) * LSEQ + (t - 1)) * 16 + c] = v;
        }
      }
    }

    // phase 1: aB = h @ Wh[:, abc0..abc0+16)
    float aB[16];
#pragma unroll
    for (int jj = 0; jj < 16; ++jj) aB[jj] = 0.0f;
#pragma unroll 4
    for (int k = 0; k < DD; ++k) {
      float hk = h_s[lane][k];
      const float* whp = &wh_s[k * GW + abc0];
#pragma unroll
      for (int jj = 0; jj < 16; ++jj)
        aB[jj] = fmaf(hk, whp[jj], aB[jj]);
    }

    // combine with gathered gx, write gates
    float gzf[16];
#pragma unroll
    for (int s = 0; s < 4; ++s) {
      gzf[s * 4 + 0] = gz4[s].x; gzf[s * 4 + 1] = gz4[s].y;
      gzf[s * 4 + 2] = gz4[s].z; gzf[s * 4 + 3] = gz4[s].w;
    }
    if (abc0 < 64) {
#pragma unroll
      for (int jj = 0; jj < 16; ++jj)
        z_s[lane][abc0 + jj] = sigmoidf_(gzf[jj] + aB[jj]);          // z
    } else {
#pragma unroll
      for (int jj = 0; jj < 16; ++jj) {
        int hj = abc0 - 64 + jj;
        float r = sigmoidf_(gzf[jj] + aB[jj]);
        r_s[lane][hj] = r * h_s[lane][hj];                            // rh
      }
    }
    __syncthreads();  // BAR1: z/rh ready

    // phase 2: aC = rh @ Wh[:, cc0..cc0+8); h update for cols hc0..hc0+8
    float aC[8];
#pragma unroll
    for (int jj = 0; jj < 8; ++jj) aC[jj] = 0.0f;
#pragma unroll 4
    for (int k = 0; k < DD; ++k) {
      float rhk = r_s[lane][k];
      const float* whc = &wh_s[k * GW + cc0];
#pragma unroll
      for (int jj = 0; jj < 8; ++jj)
        aC[jj] = fmaf(rhk, whc[jj], aC[jj]);
    }
    float gcf[8];
#pragma unroll
    for (int s = 0; s < 2; ++s) {
      gcf[s * 4 + 0] = gc4[s].x; gcf[s * 4 + 1] = gc4[s].y;
      gcf[s * 4 + 2] = gc4[s].z; gcf[s * 4 + 3] = gc4[s].w;
    }
#pragma unroll
    for (int jj = 0; jj < 8; ++jj) {
      int j = hc0 + jj;
      float z    = z_s[lane][j];
      float hold = h_s[lane][j];
      float hh = tanhf(gcf[jj] + aC[jj]);
      h_s[lane][j] = z * hold + (1.0f - z) * hh;
    }

    // issue gathers for t+1 (gc4 consumed above; latency hides under BAR2+p1)
    if (t < LSEQ - 1) {
      li_cur = li_next;
      const float4* g = reinterpret_cast<const float4*>(gx) + (size_t)li_cur * (GW / 4);
#pragma unroll
      for (int s = 0; s < 4; ++s) gz4[s] = g[abc0 / 4 + s];
#pragma unroll
      for (int s = 0; s < 2; ++s) gc4[s] = g[cc0 / 4 + s];
    }
    __syncthreads();  // BAR2: h updated; z/r free
  }

  // final store: out(7) -> seq row 7 (carried state)
#pragma unroll
  for (int s = 0; s < 2; ++s) {
    int slot = tid + 512 * s;
    int p = slot >> 4, c = slot & 15;
    if (p0 + p < NPATHS) {
      float4 v = make_float4(h_s[p][c * 4 + 0], h_s[p][c * 4 + 1],
                             h_s[p][c * 4 + 2], h_s[p][c * 4 + 3]);
      reinterpret_cast<float4*>(seq_h)[((p0 + p) * LSEQ + 7) * 16 + c] = v;
    }
  }
}

// ============================================================================
// path GRU v5 (fallback when ws too small for gx): verified round 5.
// ============================================================================
__global__ __launch_bounds__(512, 1) void path_gru_v5_kernel(
    const float* __restrict__ link_state,
    float* __restrict__ seq_h,
    const int* __restrict__ links,
    const float* __restrict__ Wx,
    const float* __restrict__ Wh,
    const float* __restrict__ bias) {
  __shared__ float wx_s[DD * GW];
  __shared__ float wh_s[DD * GW];
  __shared__ float h_s[64][65];
  __shared__ float x_s[64][65];
  __shared__ float r_s[64][65];

  const int tid  = threadIdx.x;
  const int lane = tid & 63;
  const int w    = __builtin_amdgcn_readfirstlane(tid >> 6);
  const int p0   = blockIdx.x * 64;

  for (int i = tid; i < (DD * GW) / 4; i += 512) {
    reinterpret_cast<float4*>(wx_s)[i] = reinterpret_cast<const float4*>(Wx)[i];
    reinterpret_cast<float4*>(wh_s)[i] = reinterpret_cast<const float4*>(Wh)[i];
  }
  for (int i = tid; i < 1024; i += 512) {
    int p = i >> 4, c = i & 15;
    int pr = min(p0 + p, NPATHS - 1);
    float4 v = reinterpret_cast<const float4*>(seq_h)[(pr * LSEQ + 7) * 16 + c];
    h_s[p][c * 4 + 0] = v.x; h_s[p][c * 4 + 1] = v.y;
    h_s[p][c * 4 + 2] = v.z; h_s[p][c * 4 + 3] = v.w;
  }

  const int abc0 = w * 16;
  const int cc0  = 128 + w * 8;
  const int hc0  = w * 8;

  float bab[16], bcc[8];
#pragma unroll
  for (int jj = 0; jj < 16; ++jj) bab[jj] = bias[abc0 + jj];
#pragma unroll
  for (int jj = 0; jj < 8;  ++jj) bcc[jj] = bias[cc0 + jj];

  float4 pf[2];
#pragma unroll
  for (int s = 0; s < 2; ++s) {
    int slot = tid + 512 * s;
    int p = slot >> 4, c = slot & 15;
    int pr = min(p0 + p, NPATHS - 1);
    int li = links[pr * LSEQ + 0];
    pf[s] = reinterpret_cast<const float4*>(link_state)[li * 16 + c];
  }
  __syncthreads();

  for (int t = 0; t < LSEQ; ++t) {
#pragma unroll
    for (int s = 0; s < 2; ++s) {
      int slot = tid + 512 * s;
      int p = slot >> 4, c = slot & 15;
      x_s[p][c * 4 + 0] = pf[s].x; x_s[p][c * 4 + 1] = pf[s].y;
      x_s[p][c * 4 + 2] = pf[s].z; x_s[p][c * 4 + 3] = pf[s].w;
    }
    __syncthreads();

    if (t < LSEQ - 1) {
#pragma unroll
      for (int s = 0; s < 2; ++s) {
        int slot = tid + 512 * s;
        int p = slot >> 4, c = slot & 15;
        int pr = min(p0 + p, NPATHS - 1);
        int li = links[pr * LSEQ + t + 1];
        pf[s] = reinterpret_cast<const float4*>(link_state)[li * 16 + c];
      }
    }
    if (t > 0) {
#pragma unroll
      for (int s = 0; s < 2; ++s) {
        int slot = tid + 512 * s;
        int p = slot >> 4, c = slot & 15;
        if (p0 + p < NPATHS) {
          float4 v = make_float4(h_s[p][c * 4 + 0], h_s[p][c * 4 + 1],
                                 h_s[p][c * 4 + 2], h_s[p][c * 4 + 3]);
          reinterpret_cast<float4*>(seq_h)[((p0 + p) * LSEQ + (t - 1)) * 16 + c] = v;
        }
      }
    }

    float aA[16], aB[16], cA[8];
#pragma unroll
    for (int jj = 0; jj < 16; ++jj) { aA[jj] = bab[jj]; aB[jj] = 0.0f; }
#pragma unroll
    for (int jj = 0; jj < 8; ++jj) cA[jj] = bcc[jj];
#pragma unroll 4
    for (int k = 0; k < DD; ++k) {
      float xk = x_s[lane][k];
      float hk = h_s[lane][k];
      const float* wxp = &wx_s[k * GW + abc0];
      const float* whp = &wh_s[k * GW + abc0];
      const float* wxc = &wx_s[k * GW + cc0];
#pragma unroll
      for (int jj = 0; jj < 16; ++jj) {
        aA[jj] = fmaf(xk, wxp[jj], aA[jj]);
        aB[jj] = fmaf(hk, whp[jj], aB[jj]);
      }
#pragma unroll
      for (int jj = 0; jj < 8; ++jj)
        cA[jj] = fmaf(xk, wxc[jj], cA[jj]);
    }
    __syncthreads();

    if (abc0 < 64) {
#pragma unroll
      for (int jj = 0; jj < 16; ++jj)
        x_s[lane][abc0 + jj] = sigmoidf_(aA[jj] + aB[jj]);
    } else {
#pragma unroll
      for (int jj = 0; jj < 16; ++jj) {
        int hj = abc0 - 64 + jj;
        float r = sigmoidf_(aA[jj] + aB[jj]);
        r_s[lane][hj] = r * h_s[lane][hj];
      }
    }
    __syncthreads();

    float aC[8];
#pragma unroll
    for (int jj = 0; jj < 8; ++jj) aC[jj] = 0.0f;
#pragma unroll 4
    for (int k = 0; k < DD; ++k) {
      float rhk = r_s[lane][k];
      const float* whc = &wh_s[k * GW + cc0];
#pragma unroll
      for (int jj = 0; jj < 8; ++jj)
        aC[jj] = fmaf(rhk, whc[jj], aC[jj]);
    }
#pragma unroll
    for (int jj = 0; jj < 8; ++jj) {
      int j = hc0 + jj;
      float z    = x_s[lane][j];
      float hold = h_s[lane][j];
      float hh = tanhf(cA[jj] + aC[jj]);
      h_s[lane][j] = z * hold + (1.0f - z) * hh;
    }
    __syncthreads();
  }

#pragma unroll
  for (int s = 0; s < 2; ++s) {
    int slot = tid + 512 * s;
    int p = slot >> 4, c = slot & 15;
    if (p0 + p < NPATHS) {
      float4 v = make_float4(h_s[p][c * 4 + 0], h_s[p][c * 4 + 1],
                             h_s[p][c * 4 + 2], h_s[p][c * 4 + 3]);
      reinterpret_cast<float4*>(seq_h)[((p0 + p) * LSEQ + 7) * 16 + c] = v;
    }
  }
}

// ============================================================================
// link GRU (verified round 5): x = CSR-gathered sum of seq_h rows.
// ============================================================================
__global__ __launch_bounds__(512, 1) void link_gru_kernel(
    float* __restrict__ link_state,
    const float* __restrict__ seq_h,
    const int* __restrict__ row_start,
    const int* __restrict__ row_end,
    const int* __restrict__ edges,
    const float* __restrict__ Wx,
    const float* __restrict__ Wh,
    const float* __restrict__ bias) {
  __shared__ float wx_s[DD * GW];
  __shared__ float wh_s[DD * GW];
  __shared__ float h_s[64][65];
  __shared__ float x_s[64][65];
  __shared__ float r_s[64][65];

  const int tid  = threadIdx.x;
  const int lane = tid & 63;
  const int w    = __builtin_amdgcn_readfirstlane(tid >> 6);
  const int l0   = blockIdx.x * 64;

  for (int i = tid; i < (DD * GW) / 4; i += 512) {
    reinterpret_cast<float4*>(wx_s)[i] = reinterpret_cast<const float4*>(Wx)[i];
    reinterpret_cast<float4*>(wh_s)[i] = reinterpret_cast<const float4*>(Wh)[i];
  }
  for (int i = tid; i < 1024; i += 512) {
    int p = i >> 4, c = i & 15;
    float4 hv = make_float4(0.f, 0.f, 0.f, 0.f);
    float4 xv = make_float4(0.f, 0.f, 0.f, 0.f);
    if (l0 + p < NLINKS) {
      hv = reinterpret_cast<const float4*>(link_state)[(l0 + p) * 16 + c];
      int rs = row_start[l0 + p], re = row_end[l0 + p];
      for (int ii = rs; ii < re; ++ii) {
        int e = edges[ii];
        float4 v = reinterpret_cast<const float4*>(seq_h)[e * 16 + c];
        xv.x += v.x; xv.y += v.y; xv.z += v.z; xv.w += v.w;
      }
    }
    h_s[p][c * 4 + 0] = hv.x; h_s[p][c * 4 + 1] = hv.y;
    h_s[p][c * 4 + 2] = hv.z; h_s[p][c * 4 + 3] = hv.w;
    x_s[p][c * 4 + 0] = xv.x; x_s[p][c * 4 + 1] = xv.y;
    x_s[p][c * 4 + 2] = xv.z; x_s[p][c * 4 + 3] = xv.w;
  }

  const int abc0 = w * 16;
  const int cc0  = 128 + w * 8;
  const int hc0  = w * 8;

  float bab[16], bcc[8];
#pragma unroll
  for (int jj = 0; jj < 16; ++jj) bab[jj] = bias[abc0 + jj];
#pragma unroll
  for (int jj = 0; jj < 8;  ++jj) bcc[jj] = bias[cc0 + jj];

  __syncthreads();

  float aA[16], aB[16], cA[8];
#pragma unroll
  for (int jj = 0; jj < 16; ++jj) { aA[jj] = bab[jj]; aB[jj] = 0.0f; }
#pragma unroll
  for (int jj = 0; jj < 8; ++jj) cA[jj] = bcc[jj];
#pragma unroll 4
  for (int k = 0; k < DD; ++k) {
    float xk = x_s[lane][k];
    float hk = h_s[lane][k];
    const float* wxp = &wx_s[k * GW + abc0];
    const float* whp = &wh_s[k * GW + abc0];
    const float* wxc = &wx_s[k * GW + cc0];
#pragma unroll
    for (int jj = 0; jj < 16; ++jj) {
      aA[jj] = fmaf(xk, wxp[jj], aA[jj]);
      aB[jj] = fmaf(hk, whp[jj], aB[jj]);
    }
#pragma unroll
    for (int jj = 0; jj < 8; ++jj)
      cA[jj] = fmaf(xk, wxc[jj], cA[jj]);
  }
  __syncthreads();

  if (abc0 < 64) {
#pragma unroll
    for (int jj = 0; jj < 16; ++jj)
      x_s[lane][abc0 + jj] = sigmoidf_(aA[jj] + aB[jj]);
  } else {
#pragma unroll
    for (int jj = 0; jj < 16; ++jj) {
      int hj = abc0 - 64 + jj;
      float r = sigmoidf_(aA[jj] + aB[jj]);
      r_s[lane][hj] = r * h_s[lane][hj];
    }
  }
  __syncthreads();

  float aC[8];
#pragma unroll
  for (int jj = 0; jj < 8; ++jj) aC[jj] = 0.0f;
#pragma unroll 4
  for (int k = 0; k < DD; ++k) {
    float rhk = r_s[lane][k];
    const float* whc = &wh_s[k * GW + cc0];
#pragma unroll
    for (int jj = 0; jj < 8; ++jj)
      aC[jj] = fmaf(rhk, whc[jj], aC[jj]);
  }
  const bool valid = (l0 + lane) < NLINKS;
#pragma unroll
  for (int jj = 0; jj < 8; ++jj) {
    int j = hc0 + jj;
    float z    = x_s[lane][j];
    float hold = h_s[lane][j];
    float hh = tanhf(cA[jj] + aC[jj]);
    float hn = z * hold + (1.0f - z) * hh;
    if (valid) link_state[(l0 + lane) * DD + j] = hn;
  }
}

// ---------------- readout MLP with exact-JAX dropout ----------------
__global__ __launch_bounds__(256, 1) void mlp_kernel(
    const float4* __restrict__ ps4, int rs4,
    const float* __restrict__ W1, const float* __restrict__ b1,
    const float* __restrict__ W2, const float* __restrict__ b2,
    const float* __restrict__ W3, const float* __restrict__ b3,
    float* __restrict__ out,
    uint32_t k1a, uint32_t k1b, uint32_t k2a, uint32_t k2b) {
  __shared__ float hbuf[64][256];

  const int tid  = threadIdx.x;
  const int lane = tid & 63;
  const int w    = __builtin_amdgcn_readfirstlane(tid >> 6);
  const int p0   = blockIdx.x * 64;
  const bool valid = (p0 + lane) < NPATHS;
  const int prow = valid ? (p0 + lane) : 0;

  float ps[DD];
  {
    const float4* src = ps4 + (size_t)prow * rs4;
#pragma unroll
    for (int c = 0; c < 16; ++c) {
      float4 v = src[c];
      ps[c * 4 + 0] = v.x; ps[c * 4 + 1] = v.y;
      ps[c * 4 + 2] = v.z; ps[c * 4 + 3] = v.w;
    }
  }

  const int cb = w * 64;
  const uint32_t base = (uint32_t)(p0 + lane) * 256u;
  float acc[64];

#pragma unroll
  for (int c = 0; c < 64; ++c) acc[c] = b1[cb + c];
#pragma unroll 2
  for (int k = 0; k < DD; ++k) {
    float pk = ps[k];
    const float* wp = &W1[k * 256 + cb];
#pragma unroll
    for (int c = 0; c < 64; ++c) acc[c] = fmaf(pk, wp[c], acc[c]);
  }
#pragma unroll 2
  for (int c = 0; c < 64; ++c) {
    int u = cb + c;
    float v = seluf_(acc[c]);
    bool keep = bern_keep(k1a, k1b, base + (uint32_t)u);
    hbuf[lane][(u + lane) & 255] = keep ? v * 2.0f : 0.0f;
  }
  __syncthreads();

#pragma unroll
  for (int c = 0; c < 64; ++c) acc[c] = b2[cb + c];
#pragma unroll 2
  for (int k = 0; k < 256; ++k) {
    float hk = hbuf[lane][(k + lane) & 255];
    const float* wp = &W2[k * 256 + cb];
#pragma unroll
    for (int c = 0; c < 64; ++c) acc[c] = fmaf(hk, wp[c], acc[c]);
  }
  __syncthreads();
#pragma unroll 2
  for (int c = 0; c < 64; ++c) {
    int u = cb + c;
    float v = seluf_(acc[c]);
    bool keep = bern_keep(k2a, k2b, base + (uint32_t)u);
    hbuf[lane][(u + lane) & 255] = keep ? v * 2.0f : 0.0f;
  }
  __syncthreads();

  if (w == 0) {
    float s = b3[0];
    for (int k = 0; k < 256; ++k)
      s = fmaf(hbuf[lane][(k + lane) & 255], W3[k], s);
    if (valid) out[p0 + lane] = s > 0.0f ? s : 0.0f;
  }
}

// ---------------- host ----------------
extern "C" void kernel_launch(void* const* d_in, const int* in_sizes, int n_in,
                              void* d_out, int out_size, void* d_ws, size_t ws_size,
                              hipStream_t stream) {
  const float* cap     = (const float*)d_in[0];
  const float* traffic = (const float*)d_in[1];
  const int*   links   = (const int*)d_in[2];
  const float* pWx = (const float*)d_in[5];
  const float* pWh = (const float*)d_in[6];
  const float* pb  = (const float*)d_in[7];
  const float* eWx = (const float*)d_in[8];
  const float* eWh = (const float*)d_in[9];
  const float* eb  = (const float*)d_in[10];
  const float* W1  = (const float*)d_in[11];
  const float* b1  = (const float*)d_in[12];
  const float* W2  = (const float*)d_in[13];
  const float* b2  = (const float*)d_in[14];
  const float* W3  = (const float*)d_in[15];
  const float* b3  = (const float*)d_in[16];
  float* out = (float*)d_out;

  uint32_t k1a, k1b, k2a, k2b;
  threefry2x32(0u, 1u, 0u, 0u, k1a, k1b);
  threefry2x32(0u, 1u, 0u, 1u, k2a, k2b);

  const size_t n_link = (size_t)NLINKS * DD;          // 1.28M floats
  const size_t n_seq  = (size_t)NPATHS * LSEQ * DD;   // 10.24M floats
  const size_t n_gx   = (size_t)NLINKS * GW;          // 3.84M floats
  const size_t csr_bytes = ((size_t)NLINKS * 3 + NEDGE) * 4;
  const size_t need_v6 = (n_link + n_seq + n_gx) * 4 + csr_bytes;

  if (ws_size >= need_v6) {
    float* link_state = (float*)d_ws;
    float* seq_h      = link_state + n_link;
    float* gx         = seq_h + n_seq;
    int*   counts     = (int*)(gx + n_gx);
    int*   row_start  = counts + NLINKS;
    int*   cursor     = row_start + NLINKS;
    int*   edges      = cursor + NLINKS;

    init_gather_kernel<<<(NLINKS * DD + 255) / 256, 256, 0, stream>>>(
        cap, traffic, link_state, seq_h, counts);
    csr_hist_kernel<<<(NEDGE + 255) / 256, 256, 0, stream>>>(links, counts);
    csr_scan_kernel<<<1, 1024, 0, stream>>>(counts, row_start, cursor);
    csr_fill_kernel<<<(NEDGE + 255) / 256, 256, 0, stream>>>(links, cursor, edges);

    for (int it = 0; it < TITER; ++it) {
      gx_kernel<<<NB, 512, 0, stream>>>(link_state, pWx, pb, gx);
      path_gru_v6_kernel<<<NB, 512, 0, stream>>>(gx, seq_h, links, pWh);
      link_gru_kernel<<<NB, 512, 0, stream>>>(link_state, seq_h,
                                              row_start, cursor, edges,
                                              eWx, eWh, eb);
    }
    mlp_kernel<<<NB, 256, 0, stream>>>(
        (const float4*)seq_h + 7 * 16, LSEQ * 16,
        W1, b1, W2, b2, W3, b3, out, k1a, k1b, k2a, k2b);
  } else {
    float* link_state = (float*)d_ws;
    float* seq_h      = link_state + n_link;
    int*   counts     = (int*)(seq_h + n_seq);
    int*   row_start  = counts + NLINKS;
    int*   cursor     = row_start + NLINKS;
    int*   edges      = cursor + NLINKS;

    init_gather_kernel<<<(NLINKS * DD + 255) / 256, 256, 0, stream>>>(
        cap, traffic, link_state, seq_h, counts);
    csr_hist_kernel<<<(NEDGE + 255) / 256, 256, 0, stream>>>(links, counts);
    csr_scan_kernel<<<1, 1024, 0, stream>>>(counts, row_start, cursor);
    csr_fill_kernel<<<(NEDGE + 255) / 256, 256, 0, stream>>>(links, cursor, edges);

    for (int it = 0; it < TITER; ++it) {
      path_gru_v5_kernel<<<NB, 512, 0, stream>>>(link_state, seq_h, links,
                                                 pWx, pWh, pb);
      link_gru_kernel<<<NB, 512, 0, stream>>>(link_state, seq_h,
                                              row_start, cursor, edges,
                                              eWx, eWh, eb);
    }
    mlp_kernel<<<NB, 256, 0, stream>>>(
        (const float4*)seq_h + 7 * 16, LSEQ * 16,
        W1, b1, W2, b2, W3, b3, out, k1a, k1b, k2a, k2b);
  }
}

// Round 8
// 2261.372 us; speedup vs baseline: 2.5711x; 1.0433x over previous
//
#include <hip/hip_runtime.h>
#include <cstdint>

// Problem constants (fixed by setup_inputs()).
#define NLINKS 20000
#define NPATHS 20000
#define LSEQ   8
#define TITER  8
#define DD     64
#define GW     192          // 3*DD gate width
#define NEDGE  (NPATHS * LSEQ)        // 160000
#define NB     ((NPATHS + 63) / 64)   // 313 blocks of 64 rows

// Soft workgroup barrier: LDS-visibility only (lgkmcnt), NO vmcnt drain —
// global loads/stores stay in flight across it (m139/m201-verified pattern).
__device__ static inline void softbar() {
  asm volatile("s_waitcnt lgkmcnt(0)" ::: "memory");
  __builtin_amdgcn_s_barrier();
  asm volatile("" ::: "memory");
}

// ---------------- Threefry-2x32 (exact JAX semantics) ----------------
__host__ __device__ static inline uint32_t rotl32(uint32_t x, unsigned r) {
  return (x << r) | (x >> (32u - r));
}

__host__ __device__ static inline void threefry2x32(uint32_t k0, uint32_t k1,
                                                    uint32_t c0, uint32_t c1,
                                                    uint32_t& o0, uint32_t& o1) {
  uint32_t ks0 = k0, ks1 = k1, ks2 = k0 ^ k1 ^ 0x1BD11BDAu;
  uint32_t x0 = c0 + ks0, x1 = c1 + ks1;
#define TF_R(r) { x0 += x1; x1 = rotl32(x1, r); x1 ^= x0; }
  TF_R(13) TF_R(15) TF_R(26) TF_R(6)  x0 += ks1; x1 += ks2 + 1u;
  TF_R(17) TF_R(29) TF_R(16) TF_R(24) x0 += ks2; x1 += ks0 + 2u;
  TF_R(13) TF_R(15) TF_R(26) TF_R(6)  x0 += ks0; x1 += ks1 + 3u;
  TF_R(17) TF_R(29) TF_R(16) TF_R(24) x0 += ks1; x1 += ks2 + 4u;
  TF_R(13) TF_R(15) TF_R(26) TF_R(6)  x0 += ks2; x1 += ks0 + 5u;
#undef TF_R
  o0 = x0; o1 = x1;
}

// bernoulli(key, 0.5, (20000,256)), flattened element j.
// jax_threefry_partitionable=True: counter (0, j), bits = o0 ^ o1.
__device__ static inline bool bern_keep(uint32_t key0, uint32_t key1, uint32_t j) {
  uint32_t o0, o1;
  threefry2x32(key0, key1, 0u, j, o0, o1);
  uint32_t bits = o0 ^ o1;
  float u = __uint_as_float((bits >> 9) | 0x3f800000u) - 1.0f;
  return u < 0.5f;
}

__device__ static inline float sigmoidf_(float x) { return 1.0f / (1.0f + expf(-x)); }
__device__ static inline float seluf_(float x) {
  const float sc = 1.0507009873554805f;
  const float al = 1.6732632423543772f;
  return x > 0.0f ? sc * x : sc * al * expm1f(x);
}

// ---------------- init + CSR build ----------------
__global__ void init_gather_kernel(const float* __restrict__ cap,
                                   const float* __restrict__ traffic,
                                   float* __restrict__ link_state,
                                   float* __restrict__ seq_h,
                                   int* __restrict__ counts) {
  int i = blockIdx.x * blockDim.x + threadIdx.x;
  if (i < NLINKS * DD)
    link_state[i] = ((i & 63) == 0) ? cap[i >> 6] : 0.0f;
  if (i < NPATHS * DD) {
    int p = i >> 6, j = i & 63;
    seq_h[(p * LSEQ + (LSEQ - 1)) * DD + j] = (j == 0) ? traffic[p] : 0.0f;
  }
  if (i < NLINKS) counts[i] = 0;
}

__global__ void csr_hist_kernel(const int* __restrict__ links,
                                int* __restrict__ counts) {
  int e = blockIdx.x * blockDim.x + threadIdx.x;
  if (e < NEDGE) atomicAdd(&counts[links[e]], 1);
}

__global__ __launch_bounds__(1024, 1) void csr_scan_kernel(
    const int* __restrict__ counts,
    int* __restrict__ row_start,
    int* __restrict__ cursor) {
  __shared__ int sc[1024];
  const int i = threadIdx.x;
  const int base = i * 20;
  int s = 0;
  for (int j = 0; j < 20; ++j) {
    int r = base + j;
    if (r < NLINKS) s += counts[r];
  }
  sc[i] = s;
  __syncthreads();
  for (int off = 1; off < 1024; off <<= 1) {
    int v = (i >= off) ? sc[i - off] : 0;
    __syncthreads();
    sc[i] += v;
    __syncthreads();
  }
  int run = sc[i] - s;
  for (int j = 0; j < 20; ++j) {
    int r = base + j;
    if (r < NLINKS) {
      row_start[r] = run;
      cursor[r] = run;
      run += counts[r];
    }
  }
}

__global__ void csr_fill_kernel(const int* __restrict__ links,
                                int* __restrict__ cursor,
                                int* __restrict__ edges) {
  int e = blockIdx.x * blockDim.x + threadIdx.x;
  if (e < NEDGE) {
    int l = links[e];
    int pos = atomicAdd(&cursor[l], 1);
    edges[pos] = e;
  }
}

// ============================================================================
// gx kernel: gx[l][0..192) = link_state[l] @ pWx + pb   (per message-pass iter)
// ============================================================================
__global__ __launch_bounds__(512, 2) void gx_kernel(
    const float* __restrict__ link_state,
    const float* __restrict__ Wx,
    const float* __restrict__ bias,
    float* __restrict__ gx) {
  __shared__ float wx_s[DD * GW];
  __shared__ float ls_s[64][65];

  const int tid  = threadIdx.x;
  const int lane = tid & 63;
  const int w    = __builtin_amdgcn_readfirstlane(tid >> 6);
  const int l0   = blockIdx.x * 64;

  for (int i = tid; i < (DD * GW) / 4; i += 512)
    reinterpret_cast<float4*>(wx_s)[i] = reinterpret_cast<const float4*>(Wx)[i];
  for (int i = tid; i < 1024; i += 512) {
    int p = i >> 4, c = i & 15;
    int lr = min(l0 + p, NLINKS - 1);
    float4 v = reinterpret_cast<const float4*>(link_state)[lr * 16 + c];
    ls_s[p][c * 4 + 0] = v.x; ls_s[p][c * 4 + 1] = v.y;
    ls_s[p][c * 4 + 2] = v.z; ls_s[p][c * 4 + 3] = v.w;
  }

  const int c0 = w * 24;
  float acc[24];
#pragma unroll
  for (int jj = 0; jj < 24; ++jj) acc[jj] = bias[c0 + jj];
  softbar();

#pragma unroll 4
  for (int k = 0; k < DD; ++k) {
    float xk = ls_s[lane][k];
    const float* wxp = &wx_s[k * GW + c0];
#pragma unroll
    for (int jj = 0; jj < 24; ++jj)
      acc[jj] = fmaf(xk, wxp[jj], acc[jj]);
  }

  if (l0 + lane < NLINKS) {
    float* dst = &gx[(size_t)(l0 + lane) * GW + c0];
#pragma unroll
    for (int s = 0; s < 6; ++s) {
      float4 v = make_float4(acc[s * 4 + 0], acc[s * 4 + 1],
                             acc[s * 4 + 2], acc[s * 4 + 3]);
      reinterpret_cast<float4*>(dst)[s] = v;
    }
  }
}

// ============================================================================
// path GRU v7: 1024 thr / 16 waves (4 per SIMD), soft barriers.
// Wave w: phase1 AB cols [8w,8w+8) (z if w<8 else rh);
//         phase2 aC cols [128+4w,+4) + h-update cols [4w,4w+4).
// Race-audit: phase1 reads h_s only, writes z_s/r_s (separate buffers);
// phase2 reads z_s/r_s (post-BAR1) and writes per-wave-disjoint h_s cols.
// Reference GRU (Python precedence): hh = tanh(xh + (r*h) @ Wh[:,2D:]).
// ============================================================================
__global__ __launch_bounds__(1024, 1) void path_gru_v7_kernel(
    const float* __restrict__ gx,
    float* __restrict__ seq_h,
    const int* __restrict__ links,
    const float* __restrict__ Wh) {
  __shared__ float wh_s[DD * GW];   // 48 KB
  __shared__ float h_s[64][65];
  __shared__ float z_s[64][65];
  __shared__ float r_s[64][65];     // rh

  const int tid  = threadIdx.x;
  const int lane = tid & 63;
  const int w    = __builtin_amdgcn_readfirstlane(tid >> 6);   // 0..15
  const int p0   = blockIdx.x * 64;

  for (int i = tid; i < (DD * GW) / 4; i += 1024)
    reinterpret_cast<float4*>(wh_s)[i] = reinterpret_cast<const float4*>(Wh)[i];
  {
    int p = tid >> 4, c = tid & 15;
    int pr = min(p0 + p, NPATHS - 1);
    float4 v = reinterpret_cast<const float4*>(seq_h)[(pr * LSEQ + 7) * 16 + c];
    h_s[p][c * 4 + 0] = v.x; h_s[p][c * 4 + 1] = v.y;
    h_s[p][c * 4 + 2] = v.z; h_s[p][c * 4 + 3] = v.w;
  }

  const int ab0 = w * 8;          // gate col base: z for w<8, r for w>=8
  const int cc0 = 128 + w * 4;    // cand col base
  const int hc0 = w * 4;          // h-update col base
  const int prow = min(p0 + lane, NPATHS - 1);
  const float4* gx4 = reinterpret_cast<const float4*>(gx);

  // gathers for t=0 (consumed at t=0 gate-write; compiler waits there)
  float4 gz0, gz1, gc0;
  {
    int li = links[prow * LSEQ + 0];
    const float4* g = gx4 + (size_t)li * (GW / 4);
    gz0 = g[ab0 / 4]; gz1 = g[ab0 / 4 + 1]; gc0 = g[cc0 / 4];
  }
  softbar();   // weights + h ready

  for (int t = 0; t < LSEQ; ++t) {
    // store out(t-1) = current h (stable through phase 1); 1 float4/thread
    if (t > 0) {
      int p = tid >> 4, c = tid & 15;
      if (p0 + p < NPATHS) {
        float4 v = make_float4(h_s[p][c * 4 + 0], h_s[p][c * 4 + 1],
                               h_s[p][c * 4 + 2], h_s[p][c * 4 + 3]);
        reinterpret_cast<float4*>(seq_h)[((p0 + p) * LSEQ + (t - 1)) * 16 + c] = v;
      }
    }

    // phase 1: aB = h @ Wh[:, ab0..ab0+8)
    float aB[8];
#pragma unroll
    for (int jj = 0; jj < 8; ++jj) aB[jj] = 0.0f;
#pragma unroll 4
    for (int k = 0; k < DD; ++k) {
      float hk = h_s[lane][k];
      const float* whp = &wh_s[k * GW + ab0];
#pragma unroll
      for (int jj = 0; jj < 8; ++jj)
        aB[jj] = fmaf(hk, whp[jj], aB[jj]);
    }

    // gate write (consumes gz; compiler inserts the vmcnt wait right here)
    float gzf[8] = {gz0.x, gz0.y, gz0.z, gz0.w, gz1.x, gz1.y, gz1.z, gz1.w};
    if (w < 8) {
#pragma unroll
      for (int jj = 0; jj < 8; ++jj)
        z_s[lane][ab0 + jj] = sigmoidf_(gzf[jj] + aB[jj]);           // z
    } else {
#pragma unroll
      for (int jj = 0; jj < 8; ++jj) {
        int hj = ab0 - 64 + jj;
        float r = sigmoidf_(gzf[jj] + aB[jj]);
        r_s[lane][hj] = r * h_s[lane][hj];                            // rh
      }
    }
    softbar();  // BAR1: z/rh visible; phase-1 h reads done

    // phase 2
    int li_n = (t < LSEQ - 1) ? links[prow * LSEQ + t + 1] : 0;

    float aC[4];
#pragma unroll
    for (int jj = 0; jj < 4; ++jj) aC[jj] = 0.0f;
#pragma unroll 4
    for (int k = 0; k < DD; ++k) {
      float rhk = r_s[lane][k];
      const float* whc = &wh_s[k * GW + cc0];
#pragma unroll
      for (int jj = 0; jj < 4; ++jj)
        aC[jj] = fmaf(rhk, whc[jj], aC[jj]);
    }
    float gcf[4] = {gc0.x, gc0.y, gc0.z, gc0.w};
#pragma unroll
    for (int jj = 0; jj < 4; ++jj) {
      int j = hc0 + jj;
      float z    = z_s[lane][j];
      float hold = h_s[lane][j];
      float hh = tanhf(gcf[jj] + aC[jj]);
      h_s[lane][j] = z * hold + (1.0f - z) * hh;
    }

    // issue gathers for t+1 AFTER last use of gz/gc; they stay in flight
    // across BAR2 + next phase 1 (soft barrier: no vmcnt drain).
    if (t < LSEQ - 1) {
      const float4* g = gx4 + (size_t)li_n * (GW / 4);
      gz0 = g[ab0 / 4]; gz1 = g[ab0 / 4 + 1]; gc0 = g[cc0 / 4];
    }
    softbar();  // BAR2: h updated; z/r free
  }

  // final store: out(7) -> seq row 7 (carried state)
  {
    int p = tid >> 4, c = tid & 15;
    if (p0 + p < NPATHS) {
      float4 v = make_float4(h_s[p][c * 4 + 0], h_s[p][c * 4 + 1],
                             h_s[p][c * 4 + 2], h_s[p][c * 4 + 3]);
      reinterpret_cast<float4*>(seq_h)[((p0 + p) * LSEQ + 7) * 16 + c] = v;
    }
  }
}

// ============================================================================
// link GRU v7b: 1024 thr / 16 waves, soft barriers, 4-batched CSR gather.
// RACE FIX vs v7: barrier between phase-1 x_s reads and z overwrite of x_s
// (round-6 structure restored; this was the round-7 failure).
// ============================================================================
__global__ __launch_bounds__(1024, 1) void link_gru_v7_kernel(
    float* __restrict__ link_state,
    const float* __restrict__ seq_h,
    const int* __restrict__ row_start,
    const int* __restrict__ row_end,
    const int* __restrict__ edges,
    const float* __restrict__ Wx,
    const float* __restrict__ Wh,
    const float* __restrict__ bias) {
  __shared__ float wx_s[DD * GW];
  __shared__ float wh_s[DD * GW];
  __shared__ float h_s[64][65];
  __shared__ float x_s[64][65];
  __shared__ float r_s[64][65];

  const int tid  = threadIdx.x;
  const int lane = tid & 63;
  const int w    = __builtin_amdgcn_readfirstlane(tid >> 6);   // 0..15
  const int l0   = blockIdx.x * 64;

  for (int i = tid; i < (DD * GW) / 4; i += 1024) {
    reinterpret_cast<float4*>(wx_s)[i] = reinterpret_cast<const float4*>(Wx)[i];
    reinterpret_cast<float4*>(wh_s)[i] = reinterpret_cast<const float4*>(Wh)[i];
  }
  {
    int p = tid >> 4, c = tid & 15;
    float4 hv = make_float4(0.f, 0.f, 0.f, 0.f);
    float4 xv = make_float4(0.f, 0.f, 0.f, 0.f);
    if (l0 + p < NLINKS) {
      hv = reinterpret_cast<const float4*>(link_state)[(l0 + p) * 16 + c];
      const float4* s4 = reinterpret_cast<const float4*>(seq_h);
      int rs = row_start[l0 + p], re = row_end[l0 + p];
      int ii = rs;
      for (; ii + 4 <= re; ii += 4) {
        int e0 = edges[ii + 0], e1 = edges[ii + 1];
        int e2 = edges[ii + 2], e3 = edges[ii + 3];
        float4 v0 = s4[e0 * 16 + c], v1 = s4[e1 * 16 + c];
        float4 v2 = s4[e2 * 16 + c], v3 = s4[e3 * 16 + c];
        xv.x += v0.x + v1.x + v2.x + v3.x;
        xv.y += v0.y + v1.y + v2.y + v3.y;
        xv.z += v0.z + v1.z + v2.z + v3.z;
        xv.w += v0.w + v1.w + v2.w + v3.w;
      }
      for (; ii < re; ++ii) {
        int e = edges[ii];
        float4 v = s4[e * 16 + c];
        xv.x += v.x; xv.y += v.y; xv.z += v.z; xv.w += v.w;
      }
    }
    h_s[p][c * 4 + 0] = hv.x; h_s[p][c * 4 + 1] = hv.y;
    h_s[p][c * 4 + 2] = hv.z; h_s[p][c * 4 + 3] = hv.w;
    x_s[p][c * 4 + 0] = xv.x; x_s[p][c * 4 + 1] = xv.y;
    x_s[p][c * 4 + 2] = xv.z; x_s[p][c * 4 + 3] = xv.w;
  }

  const int ab0 = w * 8;
  const int cc0 = 128 + w * 4;
  const int hc0 = w * 4;

  float bab[8], bcc[4];
#pragma unroll
  for (int jj = 0; jj < 8; ++jj) bab[jj] = bias[ab0 + jj];
#pragma unroll
  for (int jj = 0; jj < 4; ++jj) bcc[jj] = bias[cc0 + jj];

  softbar();

  // phase 1: aA = x@Wx, aB = h@Wh (8 cols), cA = x@Wx cand (4 cols)
  float aA[8], aB[8], cA[4];
#pragma unroll
  for (int jj = 0; jj < 8; ++jj) { aA[jj] = bab[jj]; aB[jj] = 0.0f; }
#pragma unroll
  for (int jj = 0; jj < 4; ++jj) cA[jj] = bcc[jj];
#pragma unroll 4
  for (int k = 0; k < DD; ++k) {
    float xk = x_s[lane][k];
    float hk = h_s[lane][k];
    const float* wxp = &wx_s[k * GW + ab0];
    const float* whp = &wh_s[k * GW + ab0];
    const float* wxc = &wx_s[k * GW + cc0];
#pragma unroll
    for (int jj = 0; jj < 8; ++jj) {
      aA[jj] = fmaf(xk, wxp[jj], aA[jj]);
      aB[jj] = fmaf(hk, whp[jj], aB[jj]);
    }
#pragma unroll
    for (int jj = 0; jj < 4; ++jj)
      cA[jj] = fmaf(xk, wxc[jj], cA[jj]);
  }
  softbar();  // RACE FIX: all waves' x_s reads complete before z overwrites x_s

  if (w < 8) {
#pragma unroll
    for (int jj = 0; jj < 8; ++jj)
      x_s[lane][ab0 + jj] = sigmoidf_(aA[jj] + aB[jj]);   // z (reuse x_s)
  } else {
#pragma unroll
    for (int jj = 0; jj < 8; ++jj) {
      int hj = ab0 - 64 + jj;
      float r = sigmoidf_(aA[jj] + aB[jj]);
      r_s[lane][hj] = r * h_s[lane][hj];
    }
  }
  softbar();

  // phase 2
  float aC[4];
#pragma unroll
  for (int jj = 0; jj < 4; ++jj) aC[jj] = 0.0f;
#pragma unroll 4
  for (int k = 0; k < DD; ++k) {
    float rhk = r_s[lane][k];
    const float* whc = &wh_s[k * GW + cc0];
#pragma unroll
    for (int jj = 0; jj < 4; ++jj)
      aC[jj] = fmaf(rhk, whc[jj], aC[jj]);
  }
  if (l0 + lane < NLINKS) {
    float4 o;
    float* ov = &o.x;
#pragma unroll
    for (int jj = 0; jj < 4; ++jj) {
      int j = hc0 + jj;
      float z    = x_s[lane][j];
      float hold = h_s[lane][j];
      float hh = tanhf(cA[jj] + aC[jj]);
      ov[jj] = z * hold + (1.0f - z) * hh;
    }
    reinterpret_cast<float4*>(&link_state[(size_t)(l0 + lane) * DD + hc0])[0] = o;
  }
}

// ============================================================================
// readout MLP v7: 1250 blocks x 256 thr, 16 paths/block, acc[16] (no spill).
// lane l: path p = l>>2, quarter q = l&3; wave w owns cols [64w,64w+64);
// lane owns cols c0 = 64w + 16q .. c0+16.
// ============================================================================
#define MB 16
__global__ __launch_bounds__(256) void mlp_v7_kernel(
    const float4* __restrict__ ps4, int rs4,
    const float* __restrict__ W1, const float* __restrict__ b1,
    const float* __restrict__ W2, const float* __restrict__ b2,
    const float* __restrict__ W3, const float* __restrict__ b3,
    float* __restrict__ out,
    uint32_t k1a, uint32_t k1b, uint32_t k2a, uint32_t k2b) {
  __shared__ float ps_s[MB][68];
  __shared__ float hbuf[MB][260];

  const int tid  = threadIdx.x;
  const int lane = tid & 63;
  const int w    = __builtin_amdgcn_readfirstlane(tid >> 6);   // 0..3
  const int p    = lane >> 2;       // path within block
  const int q    = lane & 3;
  const int p0   = blockIdx.x * MB; // 1250*16 = 20000 exactly
  const int c0   = w * 64 + q * 16;

  // stage path_state tile: 256 float4 slots, 1/thread
  {
    int pr = tid >> 4, c = tid & 15;
    float4 v = ps4[(size_t)(p0 + pr) * rs4 + c];
    ps_s[pr][c * 4 + 0] = v.x; ps_s[pr][c * 4 + 1] = v.y;
    ps_s[pr][c * 4 + 2] = v.z; ps_s[pr][c * 4 + 3] = v.w;
  }

  float acc[16];
#pragma unroll
  for (int j = 0; j < 16; ++j) acc[j] = b1[c0 + j];
  softbar();

  // layer 1: k = 64
#pragma unroll 4
  for (int k = 0; k < DD; ++k) {
    float pk = ps_s[p][k];
    const float* wp = &W1[k * 256 + c0];
#pragma unroll
    for (int j = 0; j < 16; ++j) acc[j] = fmaf(pk, wp[j], acc[j]);
  }
  {
    const uint32_t base = (uint32_t)(p0 + p) * 256u + (uint32_t)c0;
#pragma unroll
    for (int j = 0; j < 16; ++j) {
      float v = seluf_(acc[j]);
      bool keep = bern_keep(k1a, k1b, base + (uint32_t)j);
      hbuf[p][c0 + j] = keep ? v * 2.0f : 0.0f;
    }
  }
  softbar();

  // layer 2: k = 256
#pragma unroll
  for (int j = 0; j < 16; ++j) acc[j] = b2[c0 + j];
#pragma unroll 2
  for (int k = 0; k < 256; ++k) {
    float hk = hbuf[p][k];
    const float* wp = &W2[k * 256 + c0];
#pragma unroll
    for (int j = 0; j < 16; ++j) acc[j] = fmaf(hk, wp[j], acc[j]);
  }
  softbar();  // all hbuf reads done before overwrite
  {
    const uint32_t base = (uint32_t)(p0 + p) * 256u + (uint32_t)c0;
#pragma unroll
    for (int j = 0; j < 16; ++j) {
      float v = seluf_(acc[j]);
      bool keep = bern_keep(k2a, k2b, base + (uint32_t)j);
      hbuf[p][c0 + j] = keep ? v * 2.0f : 0.0f;
    }
  }
  softbar();

  // layer 3: 256 -> 1, relu. Wave 0: lane (p,q) reduces k in [64q, 64q+64).
  if (w == 0) {
    float s = 0.0f;
    const int kb = q * 64;
#pragma unroll 4
    for (int k = 0; k < 64; ++k)
      s = fmaf(hbuf[p][kb + k], W3[kb + k], s);
    s += __shfl_xor(s, 1);
    s += __shfl_xor(s, 2);
    if (q == 0) {
      float r = s + b3[0];
      out[p0 + p] = r > 0.0f ? r : 0.0f;
    }
  }
}

// ---------------- host ----------------
extern "C" void kernel_launch(void* const* d_in, const int* in_sizes, int n_in,
                              void* d_out, int out_size, void* d_ws, size_t ws_size,
                              hipStream_t stream) {
  const float* cap     = (const float*)d_in[0];
  const float* traffic = (const float*)d_in[1];
  const int*   links   = (const int*)d_in[2];
  const float* pWx = (const float*)d_in[5];
  const float* pWh = (const float*)d_in[6];
  const float* pb  = (const float*)d_in[7];
  const float* eWx = (const float*)d_in[8];
  const float* eWh = (const float*)d_in[9];
  const float* eb  = (const float*)d_in[10];
  const float* W1  = (const float*)d_in[11];
  const float* b1  = (const float*)d_in[12];
  const float* W2  = (const float*)d_in[13];
  const float* b2  = (const float*)d_in[14];
  const float* W3  = (const float*)d_in[15];
  const float* b3  = (const float*)d_in[16];
  float* out = (float*)d_out;

  uint32_t k1a, k1b, k2a, k2b;
  threefry2x32(0u, 1u, 0u, 0u, k1a, k1b);
  threefry2x32(0u, 1u, 0u, 1u, k2a, k2b);

  const size_t n_link = (size_t)NLINKS * DD;
  const size_t n_seq  = (size_t)NPATHS * LSEQ * DD;
  const size_t n_gx   = (size_t)NLINKS * GW;

  float* link_state = (float*)d_ws;
  float* seq_h      = link_state + n_link;
  float* gx         = seq_h + n_seq;
  int*   counts     = (int*)(gx + n_gx);
  int*   row_start  = counts + NLINKS;
  int*   cursor     = row_start + NLINKS;
  int*   edges      = cursor + NLINKS;

  init_gather_kernel<<<(NLINKS * DD + 255) / 256, 256, 0, stream>>>(
      cap, traffic, link_state, seq_h, counts);
  csr_hist_kernel<<<(NEDGE + 255) / 256, 256, 0, stream>>>(links, counts);
  csr_scan_kernel<<<1, 1024, 0, stream>>>(counts, row_start, cursor);
  csr_fill_kernel<<<(NEDGE + 255) / 256, 256, 0, stream>>>(links, cursor, edges);

  for (int it = 0; it < TITER; ++it) {
    gx_kernel<<<NB, 512, 0, stream>>>(link_state, pWx, pb, gx);
    path_gru_v7_kernel<<<NB, 1024, 0, stream>>>(gx, seq_h, links, pWh);
    link_gru_v7_kernel<<<NB, 1024, 0, stream>>>(link_state, seq_h,
                                                row_start, cursor, edges,
                                                eWx, eWh, eb);
  }
  mlp_v7_kernel<<<NPATHS / MB, 256, 0, stream>>>(
      (const float4*)seq_h + 7 * 16, LSEQ * 16,
      W1, b1, W2, b2, W3, b3, out, k1a, k1b, k2a, k2b);
}

// Round 9
// 2025.270 us; speedup vs baseline: 2.8708x; 1.1166x over previous
//
#include <hip/hip_runtime.h>
#include <cstdint>

// Problem constants (fixed by setup_inputs()).
#define NLINKS 20000
#define NPATHS 20000
#define LSEQ   8
#define TITER  8
#define DD     64
#define GW     192          // 3*DD gate width
#define NEDGE  (NPATHS * LSEQ)        // 160000
#define NB     ((NPATHS + 63) / 64)   // 313 blocks of 64 rows

// Soft workgroup barrier: LDS-visibility only (lgkmcnt), NO vmcnt drain —
// global loads/stores stay in flight across it (m139/m201-verified pattern).
__device__ static inline void softbar() {
  asm volatile("s_waitcnt lgkmcnt(0)" ::: "memory");
  __builtin_amdgcn_s_barrier();
  asm volatile("" ::: "memory");
}

// ---------------- Threefry-2x32 (exact JAX semantics) ----------------
__host__ __device__ static inline uint32_t rotl32(uint32_t x, unsigned r) {
  return (x << r) | (x >> (32u - r));
}

__host__ __device__ static inline void threefry2x32(uint32_t k0, uint32_t k1,
                                                    uint32_t c0, uint32_t c1,
                                                    uint32_t& o0, uint32_t& o1) {
  uint32_t ks0 = k0, ks1 = k1, ks2 = k0 ^ k1 ^ 0x1BD11BDAu;
  uint32_t x0 = c0 + ks0, x1 = c1 + ks1;
#define TF_R(r) { x0 += x1; x1 = rotl32(x1, r); x1 ^= x0; }
  TF_R(13) TF_R(15) TF_R(26) TF_R(6)  x0 += ks1; x1 += ks2 + 1u;
  TF_R(17) TF_R(29) TF_R(16) TF_R(24) x0 += ks2; x1 += ks0 + 2u;
  TF_R(13) TF_R(15) TF_R(26) TF_R(6)  x0 += ks0; x1 += ks1 + 3u;
  TF_R(17) TF_R(29) TF_R(16) TF_R(24) x0 += ks1; x1 += ks2 + 4u;
  TF_R(13) TF_R(15) TF_R(26) TF_R(6)  x0 += ks2; x1 += ks0 + 5u;
#undef TF_R
  o0 = x0; o1 = x1;
}

// bernoulli(key, 0.5, (20000,256)), flattened element j.
// jax_threefry_partitionable=True: counter (0, j), bits = o0 ^ o1.
__device__ static inline bool bern_keep(uint32_t key0, uint32_t key1, uint32_t j) {
  uint32_t o0, o1;
  threefry2x32(key0, key1, 0u, j, o0, o1);
  uint32_t bits = o0 ^ o1;
  float u = __uint_as_float((bits >> 9) | 0x3f800000u) - 1.0f;
  return u < 0.5f;
}

__device__ static inline float sigmoidf_(float x) { return 1.0f / (1.0f + expf(-x)); }
__device__ static inline float seluf_(float x) {
  const float sc = 1.0507009873554805f;
  const float al = 1.6732632423543772f;
  return x > 0.0f ? sc * x : sc * al * expm1f(x);
}

// ---------------- init + CSR build ----------------
__global__ void init_gather_kernel(const float* __restrict__ cap,
                                   const float* __restrict__ traffic,
                                   float* __restrict__ link_state,
                                   float* __restrict__ seq_h,
                                   int* __restrict__ counts) {
  int i = blockIdx.x * blockDim.x + threadIdx.x;
  if (i < NLINKS * DD)
    link_state[i] = ((i & 63) == 0) ? cap[i >> 6] : 0.0f;
  if (i < NPATHS * DD) {
    int p = i >> 6, j = i & 63;
    seq_h[(p * LSEQ + (LSEQ - 1)) * DD + j] = (j == 0) ? traffic[p] : 0.0f;
  }
  if (i < NLINKS) counts[i] = 0;
}

__global__ void csr_hist_kernel(const int* __restrict__ links,
                                int* __restrict__ counts) {
  int e = blockIdx.x * blockDim.x + threadIdx.x;
  if (e < NEDGE) atomicAdd(&counts[links[e]], 1);
}

__global__ __launch_bounds__(1024, 1) void csr_scan_kernel(
    const int* __restrict__ counts,
    int* __restrict__ row_start,
    int* __restrict__ cursor) {
  __shared__ int sc[1024];
  const int i = threadIdx.x;
  const int base = i * 20;
  int s = 0;
  for (int j = 0; j < 20; ++j) {
    int r = base + j;
    if (r < NLINKS) s += counts[r];
  }
  sc[i] = s;
  __syncthreads();
  for (int off = 1; off < 1024; off <<= 1) {
    int v = (i >= off) ? sc[i - off] : 0;
    __syncthreads();
    sc[i] += v;
    __syncthreads();
  }
  int run = sc[i] - s;
  for (int j = 0; j < 20; ++j) {
    int r = base + j;
    if (r < NLINKS) {
      row_start[r] = run;
      cursor[r] = run;
      run += counts[r];
    }
  }
}

__global__ void csr_fill_kernel(const int* __restrict__ links,
                                int* __restrict__ cursor,
                                int* __restrict__ edges) {
  int e = blockIdx.x * blockDim.x + threadIdx.x;
  if (e < NEDGE) {
    int l = links[e];
    int pos = atomicAdd(&cursor[l], 1);
    edges[pos] = e;
  }
}

// ============================================================================
// gx kernel: gx[l][0..192) = link_state[l] @ pWx + pb   (per message-pass iter)
// ============================================================================
__global__ __launch_bounds__(512, 2) void gx_kernel(
    const float* __restrict__ link_state,
    const float* __restrict__ Wx,
    const float* __restrict__ bias,
    float* __restrict__ gx) {
  __shared__ float wx_s[DD * GW];
  __shared__ float ls_s[64][65];

  const int tid  = threadIdx.x;
  const int lane = tid & 63;
  const int w    = __builtin_amdgcn_readfirstlane(tid >> 6);
  const int l0   = blockIdx.x * 64;

  for (int i = tid; i < (DD * GW) / 4; i += 512)
    reinterpret_cast<float4*>(wx_s)[i] = reinterpret_cast<const float4*>(Wx)[i];
  for (int i = tid; i < 1024; i += 512) {
    int p = i >> 4, c = i & 15;
    int lr = min(l0 + p, NLINKS - 1);
    float4 v = reinterpret_cast<const float4*>(link_state)[lr * 16 + c];
    ls_s[p][c * 4 + 0] = v.x; ls_s[p][c * 4 + 1] = v.y;
    ls_s[p][c * 4 + 2] = v.z; ls_s[p][c * 4 + 3] = v.w;
  }

  const int c0 = w * 24;
  float acc[24];
#pragma unroll
  for (int jj = 0; jj < 24; ++jj) acc[jj] = bias[c0 + jj];
  softbar();

#pragma unroll 4
  for (int k = 0; k < DD; ++k) {
    float xk = ls_s[lane][k];
    const float* wxp = &wx_s[k * GW + c0];
#pragma unroll
    for (int jj = 0; jj < 24; ++jj)
      acc[jj] = fmaf(xk, wxp[jj], acc[jj]);
  }

  if (l0 + lane < NLINKS) {
    float* dst = &gx[(size_t)(l0 + lane) * GW + c0];
#pragma unroll
    for (int s = 0; s < 6; ++s) {
      float4 v = make_float4(acc[s * 4 + 0], acc[s * 4 + 1],
                             acc[s * 4 + 2], acc[s * 4 + 3]);
      reinterpret_cast<float4*>(dst)[s] = v;
    }
  }
}

// ============================================================================
// path GRU v7 (verified round 8): 1024 thr / 16 waves, soft barriers.
// Reference GRU (Python precedence): hh = tanh(xh + (r*h) @ Wh[:,2D:]).
// ============================================================================
__global__ __launch_bounds__(1024, 1) void path_gru_v7_kernel(
    const float* __restrict__ gx,
    float* __restrict__ seq_h,
    const int* __restrict__ links,
    const float* __restrict__ Wh) {
  __shared__ float wh_s[DD * GW];   // 48 KB
  __shared__ float h_s[64][65];
  __shared__ float z_s[64][65];
  __shared__ float r_s[64][65];     // rh

  const int tid  = threadIdx.x;
  const int lane = tid & 63;
  const int w    = __builtin_amdgcn_readfirstlane(tid >> 6);   // 0..15
  const int p0   = blockIdx.x * 64;

  for (int i = tid; i < (DD * GW) / 4; i += 1024)
    reinterpret_cast<float4*>(wh_s)[i] = reinterpret_cast<const float4*>(Wh)[i];
  {
    int p = tid >> 4, c = tid & 15;
    int pr = min(p0 + p, NPATHS - 1);
    float4 v = reinterpret_cast<const float4*>(seq_h)[(pr * LSEQ + 7) * 16 + c];
    h_s[p][c * 4 + 0] = v.x; h_s[p][c * 4 + 1] = v.y;
    h_s[p][c * 4 + 2] = v.z; h_s[p][c * 4 + 3] = v.w;
  }

  const int ab0 = w * 8;          // gate col base: z for w<8, r for w>=8
  const int cc0 = 128 + w * 4;    // cand col base
  const int hc0 = w * 4;          // h-update col base
  const int prow = min(p0 + lane, NPATHS - 1);
  const float4* gx4 = reinterpret_cast<const float4*>(gx);

  // gathers for t=0 (consumed at t=0 gate-write; compiler waits there)
  float4 gz0, gz1, gc0;
  {
    int li = links[prow * LSEQ + 0];
    const float4* g = gx4 + (size_t)li * (GW / 4);
    gz0 = g[ab0 / 4]; gz1 = g[ab0 / 4 + 1]; gc0 = g[cc0 / 4];
  }
  softbar();   // weights + h ready

  for (int t = 0; t < LSEQ; ++t) {
    // store out(t-1) = current h (stable through phase 1); 1 float4/thread
    if (t > 0) {
      int p = tid >> 4, c = tid & 15;
      if (p0 + p < NPATHS) {
        float4 v = make_float4(h_s[p][c * 4 + 0], h_s[p][c * 4 + 1],
                               h_s[p][c * 4 + 2], h_s[p][c * 4 + 3]);
        reinterpret_cast<float4*>(seq_h)[((p0 + p) * LSEQ + (t - 1)) * 16 + c] = v;
      }
    }

    // phase 1: aB = h @ Wh[:, ab0..ab0+8)
    float aB[8];
#pragma unroll
    for (int jj = 0; jj < 8; ++jj) aB[jj] = 0.0f;
#pragma unroll 4
    for (int k = 0; k < DD; ++k) {
      float hk = h_s[lane][k];
      const float* whp = &wh_s[k * GW + ab0];
#pragma unroll
      for (int jj = 0; jj < 8; ++jj)
        aB[jj] = fmaf(hk, whp[jj], aB[jj]);
    }

    // gate write (consumes gz; compiler inserts the vmcnt wait right here)
    float gzf[8] = {gz0.x, gz0.y, gz0.z, gz0.w, gz1.x, gz1.y, gz1.z, gz1.w};
    if (w < 8) {
#pragma unroll
      for (int jj = 0; jj < 8; ++jj)
        z_s[lane][ab0 + jj] = sigmoidf_(gzf[jj] + aB[jj]);           // z
    } else {
#pragma unroll
      for (int jj = 0; jj < 8; ++jj) {
        int hj = ab0 - 64 + jj;
        float r = sigmoidf_(gzf[jj] + aB[jj]);
        r_s[lane][hj] = r * h_s[lane][hj];                            // rh
      }
    }
    softbar();  // BAR1: z/rh visible; phase-1 h reads done

    // phase 2
    int li_n = (t < LSEQ - 1) ? links[prow * LSEQ + t + 1] : 0;

    float aC[4];
#pragma unroll
    for (int jj = 0; jj < 4; ++jj) aC[jj] = 0.0f;
#pragma unroll 4
    for (int k = 0; k < DD; ++k) {
      float rhk = r_s[lane][k];
      const float* whc = &wh_s[k * GW + cc0];
#pragma unroll
      for (int jj = 0; jj < 4; ++jj)
        aC[jj] = fmaf(rhk, whc[jj], aC[jj]);
    }
    float gcf[4] = {gc0.x, gc0.y, gc0.z, gc0.w};
#pragma unroll
    for (int jj = 0; jj < 4; ++jj) {
      int j = hc0 + jj;
      float z    = z_s[lane][j];
      float hold = h_s[lane][j];
      float hh = tanhf(gcf[jj] + aC[jj]);
      h_s[lane][j] = z * hold + (1.0f - z) * hh;
    }

    // issue gathers for t+1 AFTER last use of gz/gc; they stay in flight
    // across BAR2 + next phase 1 (soft barrier: no vmcnt drain).
    if (t < LSEQ - 1) {
      const float4* g = gx4 + (size_t)li_n * (GW / 4);
      gz0 = g[ab0 / 4]; gz1 = g[ab0 / 4 + 1]; gc0 = g[cc0 / 4];
    }
    softbar();  // BAR2: h updated; z/r free
  }

  // final store: out(7) -> seq row 7 (carried state)
  {
    int p = tid >> 4, c = tid & 15;
    if (p0 + p < NPATHS) {
      float4 v = make_float4(h_s[p][c * 4 + 0], h_s[p][c * 4 + 1],
                             h_s[p][c * 4 + 2], h_s[p][c * 4 + 3]);
      reinterpret_cast<float4*>(seq_h)[((p0 + p) * LSEQ + 7) * 16 + c] = v;
    }
  }
}

// ============================================================================
// link GRU v7b (verified round 8): 1024 thr / 16 waves, soft barriers.
// ============================================================================
__global__ __launch_bounds__(1024, 1) void link_gru_v7_kernel(
    float* __restrict__ link_state,
    const float* __restrict__ seq_h,
    const int* __restrict__ row_start,
    const int* __restrict__ row_end,
    const int* __restrict__ edges,
    const float* __restrict__ Wx,
    const float* __restrict__ Wh,
    const float* __restrict__ bias) {
  __shared__ float wx_s[DD * GW];
  __shared__ float wh_s[DD * GW];
  __shared__ float h_s[64][65];
  __shared__ float x_s[64][65];
  __shared__ float r_s[64][65];

  const int tid  = threadIdx.x;
  const int lane = tid & 63;
  const int w    = __builtin_amdgcn_readfirstlane(tid >> 6);   // 0..15
  const int l0   = blockIdx.x * 64;

  for (int i = tid; i < (DD * GW) / 4; i += 1024) {
    reinterpret_cast<float4*>(wx_s)[i] = reinterpret_cast<const float4*>(Wx)[i];
    reinterpret_cast<float4*>(wh_s)[i] = reinterpret_cast<const float4*>(Wh)[i];
  }
  {
    int p = tid >> 4, c = tid & 15;
    float4 hv = make_float4(0.f, 0.f, 0.f, 0.f);
    float4 xv = make_float4(0.f, 0.f, 0.f, 0.f);
    if (l0 + p < NLINKS) {
      hv = reinterpret_cast<const float4*>(link_state)[(l0 + p) * 16 + c];
      const float4* s4 = reinterpret_cast<const float4*>(seq_h);
      int rs = row_start[l0 + p], re = row_end[l0 + p];
      int ii = rs;
      for (; ii + 4 <= re; ii += 4) {
        int e0 = edges[ii + 0], e1 = edges[ii + 1];
        int e2 = edges[ii + 2], e3 = edges[ii + 3];
        float4 v0 = s4[e0 * 16 + c], v1 = s4[e1 * 16 + c];
        float4 v2 = s4[e2 * 16 + c], v3 = s4[e3 * 16 + c];
        xv.x += v0.x + v1.x + v2.x + v3.x;
        xv.y += v0.y + v1.y + v2.y + v3.y;
        xv.z += v0.z + v1.z + v2.z + v3.z;
        xv.w += v0.w + v1.w + v2.w + v3.w;
      }
      for (; ii < re; ++ii) {
        int e = edges[ii];
        float4 v = s4[e * 16 + c];
        xv.x += v.x; xv.y += v.y; xv.z += v.z; xv.w += v.w;
      }
    }
    h_s[p][c * 4 + 0] = hv.x; h_s[p][c * 4 + 1] = hv.y;
    h_s[p][c * 4 + 2] = hv.z; h_s[p][c * 4 + 3] = hv.w;
    x_s[p][c * 4 + 0] = xv.x; x_s[p][c * 4 + 1] = xv.y;
    x_s[p][c * 4 + 2] = xv.z; x_s[p][c * 4 + 3] = xv.w;
  }

  const int ab0 = w * 8;
  const int cc0 = 128 + w * 4;
  const int hc0 = w * 4;

  float bab[8], bcc[4];
#pragma unroll
  for (int jj = 0; jj < 8; ++jj) bab[jj] = bias[ab0 + jj];
#pragma unroll
  for (int jj = 0; jj < 4; ++jj) bcc[jj] = bias[cc0 + jj];

  softbar();

  // phase 1: aA = x@Wx, aB = h@Wh (8 cols), cA = x@Wx cand (4 cols)
  float aA[8], aB[8], cA[4];
#pragma unroll
  for (int jj = 0; jj < 8; ++jj) { aA[jj] = bab[jj]; aB[jj] = 0.0f; }
#pragma unroll
  for (int jj = 0; jj < 4; ++jj) cA[jj] = bcc[jj];
#pragma unroll 4
  for (int k = 0; k < DD; ++k) {
    float xk = x_s[lane][k];
    float hk = h_s[lane][k];
    const float* wxp = &wx_s[k * GW + ab0];
    const float* whp = &wh_s[k * GW + ab0];
    const float* wxc = &wx_s[k * GW + cc0];
#pragma unroll
    for (int jj = 0; jj < 8; ++jj) {
      aA[jj] = fmaf(xk, wxp[jj], aA[jj]);
      aB[jj] = fmaf(hk, whp[jj], aB[jj]);
    }
#pragma unroll
    for (int jj = 0; jj < 4; ++jj)
      cA[jj] = fmaf(xk, wxc[jj], cA[jj]);
  }
  softbar();  // all waves' x_s reads complete before z overwrites x_s

  if (w < 8) {
#pragma unroll
    for (int jj = 0; jj < 8; ++jj)
      x_s[lane][ab0 + jj] = sigmoidf_(aA[jj] + aB[jj]);   // z (reuse x_s)
  } else {
#pragma unroll
    for (int jj = 0; jj < 8; ++jj) {
      int hj = ab0 - 64 + jj;
      float r = sigmoidf_(aA[jj] + aB[jj]);
      r_s[lane][hj] = r * h_s[lane][hj];
    }
  }
  softbar();

  // phase 2
  float aC[4];
#pragma unroll
  for (int jj = 0; jj < 4; ++jj) aC[jj] = 0.0f;
#pragma unroll 4
  for (int k = 0; k < DD; ++k) {
    float rhk = r_s[lane][k];
    const float* whc = &wh_s[k * GW + cc0];
#pragma unroll
    for (int jj = 0; jj < 4; ++jj)
      aC[jj] = fmaf(rhk, whc[jj], aC[jj]);
  }
  if (l0 + lane < NLINKS) {
    float4 o;
    float* ov = &o.x;
#pragma unroll
    for (int jj = 0; jj < 4; ++jj) {
      int j = hc0 + jj;
      float z    = x_s[lane][j];
      float hold = h_s[lane][j];
      float hh = tanhf(cA[jj] + aC[jj]);
      ov[jj] = z * hold + (1.0f - z) * hh;
    }
    reinterpret_cast<float4*>(&link_state[(size_t)(l0 + lane) * DD + hc0])[0] = o;
  }
}

// ============================================================================
// MLP v8: 313 blocks x 1024 thr (16 waves), lane = path, wave w owns cols
// [16w, 16w+16). acc[16] (no spill). Weight addresses are wave-uniform ->
// scalar s_load stream (no per-lane VMEM, no redundancy). All LDS strides
// ~= 1 mod 32 -> <=2-way bank access (free). Dropout-2 + W3 partial fused
// in registers; one cross-wave reduce via part_s.
// ============================================================================
__global__ __launch_bounds__(1024, 1) void mlp_v8_kernel(
    const float4* __restrict__ ps4, int rs4,
    const float* __restrict__ W1, const float* __restrict__ b1,
    const float* __restrict__ W2, const float* __restrict__ b2,
    const float* __restrict__ W3, const float* __restrict__ b3,
    float* __restrict__ out,
    uint32_t k1a, uint32_t k1b, uint32_t k2a, uint32_t k2b) {
  __shared__ float ps_s[64][65];     // 16.6 KB (stride 65 = 2-way)
  __shared__ float hbuf[64][257];    // 65.8 KB (stride 257 = 2-way)
  __shared__ float part_s[64][17];   //  4.4 KB (stride 17 = 2-way)

  const int tid  = threadIdx.x;
  const int lane = tid & 63;
  const int w    = __builtin_amdgcn_readfirstlane(tid >> 6);   // 0..15
  const int p0   = blockIdx.x * 64;
  const int c0   = w * 16;

  // stage path_state: 1024 float4 slots, 1/thread
  {
    int p = tid >> 4, c = tid & 15;
    int pr = min(p0 + p, NPATHS - 1);
    float4 v = ps4[(size_t)pr * rs4 + c];
    ps_s[p][c * 4 + 0] = v.x; ps_s[p][c * 4 + 1] = v.y;
    ps_s[p][c * 4 + 2] = v.z; ps_s[p][c * 4 + 3] = v.w;
  }

  float acc[16];
#pragma unroll
  for (int j = 0; j < 16; ++j) acc[j] = b1[c0 + j];
  softbar();

  const uint32_t base = (uint32_t)(p0 + lane) * 256u + (uint32_t)c0;

  // layer 1: k = 64; W1 row slice is wave-uniform -> s_load
#pragma unroll 2
  for (int k = 0; k < DD; ++k) {
    float pk = ps_s[lane][k];
    const float* wp = &W1[k * 256 + c0];
#pragma unroll
    for (int j = 0; j < 16; ++j) acc[j] = fmaf(pk, wp[j], acc[j]);
  }
#pragma unroll
  for (int j = 0; j < 16; ++j) {
    float v = seluf_(acc[j]);
    bool keep = bern_keep(k1a, k1b, base + (uint32_t)j);
    hbuf[lane][c0 + j] = keep ? v * 2.0f : 0.0f;
  }
  softbar();

  // layer 2: k = 256; W2 row slice wave-uniform -> s_load
#pragma unroll
  for (int j = 0; j < 16; ++j) acc[j] = b2[c0 + j];
#pragma unroll 2
  for (int k = 0; k < 256; ++k) {
    float hk = hbuf[lane][k];
    const float* wp = &W2[k * 256 + c0];
#pragma unroll
    for (int j = 0; j < 16; ++j) acc[j] = fmaf(hk, wp[j], acc[j]);
  }

  // dropout 2 + layer-3 partial, fused in registers (h2 never hits LDS)
  {
    float s = 0.0f;
#pragma unroll
    for (int j = 0; j < 16; ++j) {
      float v = seluf_(acc[j]);
      bool keep = bern_keep(k2a, k2b, base + (uint32_t)j);
      float h2 = keep ? v * 2.0f : 0.0f;
      s = fmaf(h2, W3[c0 + j], s);
    }
    part_s[lane][w] = s;
  }
  softbar();

  if (w == 0) {
    float t = b3[0];
#pragma unroll
    for (int ww = 0; ww < 16; ++ww) t += part_s[lane][ww];
    if (p0 + lane < NPATHS) out[p0 + lane] = t > 0.0f ? t : 0.0f;
  }
}

// ---------------- host ----------------
extern "C" void kernel_launch(void* const* d_in, const int* in_sizes, int n_in,
                              void* d_out, int out_size, void* d_ws, size_t ws_size,
                              hipStream_t stream) {
  const float* cap     = (const float*)d_in[0];
  const float* traffic = (const float*)d_in[1];
  const int*   links   = (const int*)d_in[2];
  const float* pWx = (const float*)d_in[5];
  const float* pWh = (const float*)d_in[6];
  const float* pb  = (const float*)d_in[7];
  const float* eWx = (const float*)d_in[8];
  const float* eWh = (const float*)d_in[9];
  const float* eb  = (const float*)d_in[10];
  const float* W1  = (const float*)d_in[11];
  const float* b1  = (const float*)d_in[12];
  const float* W2  = (const float*)d_in[13];
  const float* b2  = (const float*)d_in[14];
  const float* W3  = (const float*)d_in[15];
  const float* b3  = (const float*)d_in[16];
  float* out = (float*)d_out;

  uint32_t k1a, k1b, k2a, k2b;
  threefry2x32(0u, 1u, 0u, 0u, k1a, k1b);
  threefry2x32(0u, 1u, 0u, 1u, k2a, k2b);

  const size_t n_link = (size_t)NLINKS * DD;
  const size_t n_seq  = (size_t)NPATHS * LSEQ * DD;
  const size_t n_gx   = (size_t)NLINKS * GW;

  float* link_state = (float*)d_ws;
  float* seq_h      = link_state + n_link;
  float* gx         = seq_h + n_seq;
  int*   counts     = (int*)(gx + n_gx);
  int*   row_start  = counts + NLINKS;
  int*   cursor     = row_start + NLINKS;
  int*   edges      = cursor + NLINKS;

  init_gather_kernel<<<(NLINKS * DD + 255) / 256, 256, 0, stream>>>(
      cap, traffic, link_state, seq_h, counts);
  csr_hist_kernel<<<(NEDGE + 255) / 256, 256, 0, stream>>>(links, counts);
  csr_scan_kernel<<<1, 1024, 0, stream>>>(counts, row_start, cursor);
  csr_fill_kernel<<<(NEDGE + 255) / 256, 256, 0, stream>>>(links, cursor, edges);

  for (int it = 0; it < TITER; ++it) {
    gx_kernel<<<NB, 512, 0, stream>>>(link_state, pWx, pb, gx);
    path_gru_v7_kernel<<<NB, 1024, 0, stream>>>(gx, seq_h, links, pWh);
    link_gru_v7_kernel<<<NB, 1024, 0, stream>>>(link_state, seq_h,
                                                row_start, cursor, edges,
                                                eWx, eWh, eb);
  }
  mlp_v8_kernel<<<NB, 1024, 0, stream>>>(
      (const float4*)seq_h + 7 * 16, LSEQ * 16,
      W1, b1, W2, b2, W3, b3, out, k1a, k1b, k2a, k2b);
}

// Round 10
// 1450.695 us; speedup vs baseline: 4.0078x; 1.3961x over previous
//
#include <hip/hip_runtime.h>
#include <cstdint>

// Problem constants (fixed by setup_inputs()).
#define NLINKS 20000
#define NPATHS 20000
#define LSEQ   8
#define TITER  8
#define DD     64
#define GW     192          // 3*DD gate width
#define NEDGE  (NPATHS * LSEQ)        // 160000
#define NB     ((NPATHS + 63) / 64)   // 313 blocks of 64 rows

// Soft workgroup barrier: LDS-visibility only (lgkmcnt), NO vmcnt drain —
// global loads/stores stay in flight across it (m139/m201-verified pattern).
__device__ static inline void softbar() {
  asm volatile("s_waitcnt lgkmcnt(0)" ::: "memory");
  __builtin_amdgcn_s_barrier();
  asm volatile("" ::: "memory");
}

// ---------------- Threefry-2x32 (exact JAX semantics) ----------------
__host__ __device__ static inline uint32_t rotl32(uint32_t x, unsigned r) {
  return (x << r) | (x >> (32u - r));
}

__host__ __device__ static inline void threefry2x32(uint32_t k0, uint32_t k1,
                                                    uint32_t c0, uint32_t c1,
                                                    uint32_t& o0, uint32_t& o1) {
  uint32_t ks0 = k0, ks1 = k1, ks2 = k0 ^ k1 ^ 0x1BD11BDAu;
  uint32_t x0 = c0 + ks0, x1 = c1 + ks1;
#define TF_R(r) { x0 += x1; x1 = rotl32(x1, r); x1 ^= x0; }
  TF_R(13) TF_R(15) TF_R(26) TF_R(6)  x0 += ks1; x1 += ks2 + 1u;
  TF_R(17) TF_R(29) TF_R(16) TF_R(24) x0 += ks2; x1 += ks0 + 2u;
  TF_R(13) TF_R(15) TF_R(26) TF_R(6)  x0 += ks0; x1 += ks1 + 3u;
  TF_R(17) TF_R(29) TF_R(16) TF_R(24) x0 += ks1; x1 += ks2 + 4u;
  TF_R(13) TF_R(15) TF_R(26) TF_R(6)  x0 += ks2; x1 += ks0 + 5u;
#undef TF_R
  o0 = x0; o1 = x1;
}

// bernoulli(key, 0.5, (20000,256)), flattened element j.
// jax_threefry_partitionable=True: counter (0, j), bits = o0 ^ o1.
__device__ static inline bool bern_keep(uint32_t key0, uint32_t key1, uint32_t j) {
  uint32_t o0, o1;
  threefry2x32(key0, key1, 0u, j, o0, o1);
  uint32_t bits = o0 ^ o1;
  float u = __uint_as_float((bits >> 9) | 0x3f800000u) - 1.0f;
  return u < 0.5f;
}

__device__ static inline float sigmoidf_(float x) { return 1.0f / (1.0f + expf(-x)); }
__device__ static inline float seluf_(float x) {
  const float sc = 1.0507009873554805f;
  const float al = 1.6732632423543772f;
  return x > 0.0f ? sc * x : sc * al * expm1f(x);
}

// ---------------- init + CSR build ----------------
__global__ void init_gather_kernel(const float* __restrict__ cap,
                                   const float* __restrict__ traffic,
                                   float* __restrict__ link_state,
                                   float* __restrict__ seq_h,
                                   int* __restrict__ counts) {
  int i = blockIdx.x * blockDim.x + threadIdx.x;
  if (i < NLINKS * DD)
    link_state[i] = ((i & 63) == 0) ? cap[i >> 6] : 0.0f;
  if (i < NPATHS * DD) {
    int p = i >> 6, j = i & 63;
    seq_h[(p * LSEQ + (LSEQ - 1)) * DD + j] = (j == 0) ? traffic[p] : 0.0f;
  }
  if (i < NLINKS) counts[i] = 0;
}

__global__ void csr_hist_kernel(const int* __restrict__ links,
                                int* __restrict__ counts) {
  int e = blockIdx.x * blockDim.x + threadIdx.x;
  if (e < NEDGE) atomicAdd(&counts[links[e]], 1);
}

__global__ __launch_bounds__(1024, 1) void csr_scan_kernel(
    const int* __restrict__ counts,
    int* __restrict__ row_start,
    int* __restrict__ cursor) {
  __shared__ int sc[1024];
  const int i = threadIdx.x;
  const int base = i * 20;
  int s = 0;
  for (int j = 0; j < 20; ++j) {
    int r = base + j;
    if (r < NLINKS) s += counts[r];
  }
  sc[i] = s;
  __syncthreads();
  for (int off = 1; off < 1024; off <<= 1) {
    int v = (i >= off) ? sc[i - off] : 0;
    __syncthreads();
    sc[i] += v;
    __syncthreads();
  }
  int run = sc[i] - s;
  for (int j = 0; j < 20; ++j) {
    int r = base + j;
    if (r < NLINKS) {
      row_start[r] = run;
      cursor[r] = run;
      run += counts[r];
    }
  }
}

__global__ void csr_fill_kernel(const int* __restrict__ links,
                                int* __restrict__ cursor,
                                int* __restrict__ edges) {
  int e = blockIdx.x * blockDim.x + threadIdx.x;
  if (e < NEDGE) {
    int l = links[e];
    int pos = atomicAdd(&cursor[l], 1);
    edges[pos] = e;
  }
}

// ============================================================================
// gx kernel v9: weights via wave-uniform scalar loads (no wx_s LDS).
// gx[l][0..192) = link_state[l] @ pWx + pb.
// ============================================================================
__global__ __launch_bounds__(512, 4) void gx_kernel(
    const float* __restrict__ link_state,
    const float* __restrict__ Wx,
    const float* __restrict__ bias,
    float* __restrict__ gx) {
  __shared__ float ls_s[64][65];

  const int tid  = threadIdx.x;
  const int lane = tid & 63;
  const int w    = __builtin_amdgcn_readfirstlane(tid >> 6);
  const int l0   = blockIdx.x * 64;

  for (int i = tid; i < 1024; i += 512) {
    int p = i >> 4, c = i & 15;
    int lr = min(l0 + p, NLINKS - 1);
    float4 v = reinterpret_cast<const float4*>(link_state)[lr * 16 + c];
    ls_s[p][c * 4 + 0] = v.x; ls_s[p][c * 4 + 1] = v.y;
    ls_s[p][c * 4 + 2] = v.z; ls_s[p][c * 4 + 3] = v.w;
  }

  const int c0 = w * 24;
  float acc[24];
#pragma unroll
  for (int jj = 0; jj < 24; ++jj) acc[jj] = bias[c0 + jj];
  softbar();

#pragma unroll 4
  for (int k = 0; k < DD; ++k) {
    float xk = ls_s[lane][k];
    const float* wxp = &Wx[k * GW + c0];   // wave-uniform -> s_load
#pragma unroll
    for (int jj = 0; jj < 24; ++jj)
      acc[jj] = fmaf(xk, wxp[jj], acc[jj]);
  }

  if (l0 + lane < NLINKS) {
    float* dst = &gx[(size_t)(l0 + lane) * GW + c0];
#pragma unroll
    for (int s = 0; s < 6; ++s) {
      float4 v = make_float4(acc[s * 4 + 0], acc[s * 4 + 1],
                             acc[s * 4 + 2], acc[s * 4 + 3]);
      reinterpret_cast<float4*>(dst)[s] = v;
    }
  }
}

// ============================================================================
// path GRU v9: weights via wave-uniform SCALAR loads from global (constant
// cache / scalar pipe) — LDS pipe now carries only h/z/r state. LDS = 50 KB
// -> 2 blocks/CU (32 waves, max occupancy). Barrier structure IDENTICAL to
// verified round-9 v7 kernel.
// Reference GRU (Python precedence): hh = tanh(xh + (r*h) @ Wh[:,2D:]).
// ============================================================================
__global__ __launch_bounds__(1024, 8) void path_gru_v9_kernel(
    const float* __restrict__ gx,
    float* __restrict__ seq_h,
    const int* __restrict__ links,
    const float* __restrict__ Wh) {
  __shared__ float h_s[64][65];
  __shared__ float z_s[64][65];
  __shared__ float r_s[64][65];     // rh

  const int tid  = threadIdx.x;
  const int lane = tid & 63;
  const int w    = __builtin_amdgcn_readfirstlane(tid >> 6);   // 0..15
  const int p0   = blockIdx.x * 64;

  {
    int p = tid >> 4, c = tid & 15;
    int pr = min(p0 + p, NPATHS - 1);
    float4 v = reinterpret_cast<const float4*>(seq_h)[(pr * LSEQ + 7) * 16 + c];
    h_s[p][c * 4 + 0] = v.x; h_s[p][c * 4 + 1] = v.y;
    h_s[p][c * 4 + 2] = v.z; h_s[p][c * 4 + 3] = v.w;
  }

  const int ab0 = w * 8;          // gate col base: z for w<8, r for w>=8
  const int cc0 = 128 + w * 4;    // cand col base
  const int hc0 = w * 4;          // h-update col base
  const int prow = min(p0 + lane, NPATHS - 1);
  const float4* gx4 = reinterpret_cast<const float4*>(gx);

  // gathers for t=0 (consumed at t=0 gate-write; compiler waits there)
  float4 gz0, gz1, gc0;
  {
    int li = links[prow * LSEQ + 0];
    const float4* g = gx4 + (size_t)li * (GW / 4);
    gz0 = g[ab0 / 4]; gz1 = g[ab0 / 4 + 1]; gc0 = g[cc0 / 4];
  }
  softbar();   // h ready

  for (int t = 0; t < LSEQ; ++t) {
    // store out(t-1) = current h (stable through phase 1); 1 float4/thread
    if (t > 0) {
      int p = tid >> 4, c = tid & 15;
      if (p0 + p < NPATHS) {
        float4 v = make_float4(h_s[p][c * 4 + 0], h_s[p][c * 4 + 1],
                               h_s[p][c * 4 + 2], h_s[p][c * 4 + 3]);
        reinterpret_cast<float4*>(seq_h)[((p0 + p) * LSEQ + (t - 1)) * 16 + c] = v;
      }
    }

    // phase 1: aB = h @ Wh[:, ab0..ab0+8)  (weights: scalar loads)
    float aB[8];
#pragma unroll
    for (int jj = 0; jj < 8; ++jj) aB[jj] = 0.0f;
#pragma unroll 4
    for (int k = 0; k < DD; ++k) {
      float hk = h_s[lane][k];
      const float* whp = &Wh[k * GW + ab0];   // wave-uniform -> s_load
#pragma unroll
      for (int jj = 0; jj < 8; ++jj)
        aB[jj] = fmaf(hk, whp[jj], aB[jj]);
    }

    // gate write (consumes gz; compiler inserts the vmcnt wait right here)
    float gzf[8] = {gz0.x, gz0.y, gz0.z, gz0.w, gz1.x, gz1.y, gz1.z, gz1.w};
    if (w < 8) {
#pragma unroll
      for (int jj = 0; jj < 8; ++jj)
        z_s[lane][ab0 + jj] = sigmoidf_(gzf[jj] + aB[jj]);           // z
    } else {
#pragma unroll
      for (int jj = 0; jj < 8; ++jj) {
        int hj = ab0 - 64 + jj;
        float r = sigmoidf_(gzf[jj] + aB[jj]);
        r_s[lane][hj] = r * h_s[lane][hj];                            // rh
      }
    }
    softbar();  // BAR1: z/rh visible; phase-1 h reads done

    // phase 2
    int li_n = (t < LSEQ - 1) ? links[prow * LSEQ + t + 1] : 0;

    float aC[4];
#pragma unroll
    for (int jj = 0; jj < 4; ++jj) aC[jj] = 0.0f;
#pragma unroll 4
    for (int k = 0; k < DD; ++k) {
      float rhk = r_s[lane][k];
      const float* whc = &Wh[k * GW + cc0];   // wave-uniform -> s_load
#pragma unroll
      for (int jj = 0; jj < 4; ++jj)
        aC[jj] = fmaf(rhk, whc[jj], aC[jj]);
    }
    float gcf[4] = {gc0.x, gc0.y, gc0.z, gc0.w};
#pragma unroll
    for (int jj = 0; jj < 4; ++jj) {
      int j = hc0 + jj;
      float z    = z_s[lane][j];
      float hold = h_s[lane][j];
      float hh = tanhf(gcf[jj] + aC[jj]);
      h_s[lane][j] = z * hold + (1.0f - z) * hh;
    }

    // issue gathers for t+1 AFTER last use of gz/gc; they stay in flight
    // across BAR2 + next phase 1 (soft barrier: no vmcnt drain).
    if (t < LSEQ - 1) {
      const float4* g = gx4 + (size_t)li_n * (GW / 4);
      gz0 = g[ab0 / 4]; gz1 = g[ab0 / 4 + 1]; gc0 = g[cc0 / 4];
    }
    softbar();  // BAR2: h updated; z/r free
  }

  // final store: out(7) -> seq row 7 (carried state)
  {
    int p = tid >> 4, c = tid & 15;
    if (p0 + p < NPATHS) {
      float4 v = make_float4(h_s[p][c * 4 + 0], h_s[p][c * 4 + 1],
                             h_s[p][c * 4 + 2], h_s[p][c * 4 + 3]);
      reinterpret_cast<float4*>(seq_h)[((p0 + p) * LSEQ + 7) * 16 + c] = v;
    }
  }
}

// ============================================================================
// link GRU v9: weights via wave-uniform scalar loads (no wx_s/wh_s LDS);
// LDS = 50 KB -> 2 blocks/CU. Barrier structure IDENTICAL to round-9 v7b.
// ============================================================================
__global__ __launch_bounds__(1024, 8) void link_gru_v9_kernel(
    float* __restrict__ link_state,
    const float* __restrict__ seq_h,
    const int* __restrict__ row_start,
    const int* __restrict__ row_end,
    const int* __restrict__ edges,
    const float* __restrict__ Wx,
    const float* __restrict__ Wh,
    const float* __restrict__ bias) {
  __shared__ float h_s[64][65];
  __shared__ float x_s[64][65];
  __shared__ float r_s[64][65];

  const int tid  = threadIdx.x;
  const int lane = tid & 63;
  const int w    = __builtin_amdgcn_readfirstlane(tid >> 6);   // 0..15
  const int l0   = blockIdx.x * 64;

  {
    int p = tid >> 4, c = tid & 15;
    float4 hv = make_float4(0.f, 0.f, 0.f, 0.f);
    float4 xv = make_float4(0.f, 0.f, 0.f, 0.f);
    if (l0 + p < NLINKS) {
      hv = reinterpret_cast<const float4*>(link_state)[(l0 + p) * 16 + c];
      const float4* s4 = reinterpret_cast<const float4*>(seq_h);
      int rs = row_start[l0 + p], re = row_end[l0 + p];
      int ii = rs;
      for (; ii + 4 <= re; ii += 4) {
        int e0 = edges[ii + 0], e1 = edges[ii + 1];
        int e2 = edges[ii + 2], e3 = edges[ii + 3];
        float4 v0 = s4[e0 * 16 + c], v1 = s4[e1 * 16 + c];
        float4 v2 = s4[e2 * 16 + c], v3 = s4[e3 * 16 + c];
        xv.x += v0.x + v1.x + v2.x + v3.x;
        xv.y += v0.y + v1.y + v2.y + v3.y;
        xv.z += v0.z + v1.z + v2.z + v3.z;
        xv.w += v0.w + v1.w + v2.w + v3.w;
      }
      for (; ii < re; ++ii) {
        int e = edges[ii];
        float4 v = s4[e * 16 + c];
        xv.x += v.x; xv.y += v.y; xv.z += v.z; xv.w += v.w;
      }
    }
    h_s[p][c * 4 + 0] = hv.x; h_s[p][c * 4 + 1] = hv.y;
    h_s[p][c * 4 + 2] = hv.z; h_s[p][c * 4 + 3] = hv.w;
    x_s[p][c * 4 + 0] = xv.x; x_s[p][c * 4 + 1] = xv.y;
    x_s[p][c * 4 + 2] = xv.z; x_s[p][c * 4 + 3] = xv.w;
  }

  const int ab0 = w * 8;
  const int cc0 = 128 + w * 4;
  const int hc0 = w * 4;

  float bab[8], bcc[4];
#pragma unroll
  for (int jj = 0; jj < 8; ++jj) bab[jj] = bias[ab0 + jj];
#pragma unroll
  for (int jj = 0; jj < 4; ++jj) bcc[jj] = bias[cc0 + jj];

  softbar();

  // phase 1: aA = x@Wx, aB = h@Wh (8 cols), cA = x@Wx cand (4 cols)
  float aA[8], aB[8], cA[4];
#pragma unroll
  for (int jj = 0; jj < 8; ++jj) { aA[jj] = bab[jj]; aB[jj] = 0.0f; }
#pragma unroll
  for (int jj = 0; jj < 4; ++jj) cA[jj] = bcc[jj];
#pragma unroll 4
  for (int k = 0; k < DD; ++k) {
    float xk = x_s[lane][k];
    float hk = h_s[lane][k];
    const float* wxp = &Wx[k * GW + ab0];   // wave-uniform -> s_load
    const float* whp = &Wh[k * GW + ab0];
    const float* wxc = &Wx[k * GW + cc0];
#pragma unroll
    for (int jj = 0; jj < 8; ++jj) {
      aA[jj] = fmaf(xk, wxp[jj], aA[jj]);
      aB[jj] = fmaf(hk, whp[jj], aB[jj]);
    }
#pragma unroll
    for (int jj = 0; jj < 4; ++jj)
      cA[jj] = fmaf(xk, wxc[jj], cA[jj]);
  }
  softbar();  // all waves' x_s reads complete before z overwrites x_s

  if (w < 8) {
#pragma unroll
    for (int jj = 0; jj < 8; ++jj)
      x_s[lane][ab0 + jj] = sigmoidf_(aA[jj] + aB[jj]);   // z (reuse x_s)
  } else {
#pragma unroll
    for (int jj = 0; jj < 8; ++jj) {
      int hj = ab0 - 64 + jj;
      float r = sigmoidf_(aA[jj] + aB[jj]);
      r_s[lane][hj] = r * h_s[lane][hj];
    }
  }
  softbar();

  // phase 2
  float aC[4];
#pragma unroll
  for (int jj = 0; jj < 4; ++jj) aC[jj] = 0.0f;
#pragma unroll 4
  for (int k = 0; k < DD; ++k) {
    float rhk = r_s[lane][k];
    const float* whc = &Wh[k * GW + cc0];   // wave-uniform -> s_load
#pragma unroll
    for (int jj = 0; jj < 4; ++jj)
      aC[jj] = fmaf(rhk, whc[jj], aC[jj]);
  }
  if (l0 + lane < NLINKS) {
    float4 o;
    float* ov = &o.x;
#pragma unroll
    for (int jj = 0; jj < 4; ++jj) {
      int j = hc0 + jj;
      float z    = x_s[lane][j];
      float hold = h_s[lane][j];
      float hh = tanhf(cA[jj] + aC[jj]);
      ov[jj] = z * hold + (1.0f - z) * hh;
    }
    reinterpret_cast<float4*>(&link_state[(size_t)(l0 + lane) * DD + hc0])[0] = o;
  }
}

// ============================================================================
// MLP v8 (verified round 9): 313 blocks x 1024 thr, lane = path, wave w owns
// cols [16w,16w+16); wave-uniform weight addresses -> s_load.
// ============================================================================
__global__ __launch_bounds__(1024, 1) void mlp_v8_kernel(
    const float4* __restrict__ ps4, int rs4,
    const float* __restrict__ W1, const float* __restrict__ b1,
    const float* __restrict__ W2, const float* __restrict__ b2,
    const float* __restrict__ W3, const float* __restrict__ b3,
    float* __restrict__ out,
    uint32_t k1a, uint32_t k1b, uint32_t k2a, uint32_t k2b) {
  __shared__ float ps_s[64][65];     // 16.6 KB (stride 65 = 2-way)
  __shared__ float hbuf[64][257];    // 65.8 KB (stride 257 = 2-way)
  __shared__ float part_s[64][17];   //  4.4 KB (stride 17 = 2-way)

  const int tid  = threadIdx.x;
  const int lane = tid & 63;
  const int w    = __builtin_amdgcn_readfirstlane(tid >> 6);   // 0..15
  const int p0   = blockIdx.x * 64;
  const int c0   = w * 16;

  // stage path_state: 1024 float4 slots, 1/thread
  {
    int p = tid >> 4, c = tid & 15;
    int pr = min(p0 + p, NPATHS - 1);
    float4 v = ps4[(size_t)pr * rs4 + c];
    ps_s[p][c * 4 + 0] = v.x; ps_s[p][c * 4 + 1] = v.y;
    ps_s[p][c * 4 + 2] = v.z; ps_s[p][c * 4 + 3] = v.w;
  }

  float acc[16];
#pragma unroll
  for (int j = 0; j < 16; ++j) acc[j] = b1[c0 + j];
  softbar();

  const uint32_t base = (uint32_t)(p0 + lane) * 256u + (uint32_t)c0;

  // layer 1: k = 64; W1 row slice is wave-uniform -> s_load
#pragma unroll 2
  for (int k = 0; k < DD; ++k) {
    float pk = ps_s[lane][k];
    const float* wp = &W1[k * 256 + c0];
#pragma unroll
    for (int j = 0; j < 16; ++j) acc[j] = fmaf(pk, wp[j], acc[j]);
  }
#pragma unroll
  for (int j = 0; j < 16; ++j) {
    float v = seluf_(acc[j]);
    bool keep = bern_keep(k1a, k1b, base + (uint32_t)j);
    hbuf[lane][c0 + j] = keep ? v * 2.0f : 0.0f;
  }
  softbar();

  // layer 2: k = 256; W2 row slice wave-uniform -> s_load
#pragma unroll
  for (int j = 0; j < 16; ++j) acc[j] = b2[c0 + j];
#pragma unroll 2
  for (int k = 0; k < 256; ++k) {
    float hk = hbuf[lane][k];
    const float* wp = &W2[k * 256 + c0];
#pragma unroll
    for (int j = 0; j < 16; ++j) acc[j] = fmaf(hk, wp[j], acc[j]);
  }

  // dropout 2 + layer-3 partial, fused in registers (h2 never hits LDS)
  {
    float s = 0.0f;
#pragma unroll
    for (int j = 0; j < 16; ++j) {
      float v = seluf_(acc[j]);
      bool keep = bern_keep(k2a, k2b, base + (uint32_t)j);
      float h2 = keep ? v * 2.0f : 0.0f;
      s = fmaf(h2, W3[c0 + j], s);
    }
    part_s[lane][w] = s;
  }
  softbar();

  if (w == 0) {
    float t = b3[0];
#pragma unroll
    for (int ww = 0; ww < 16; ++ww) t += part_s[lane][ww];
    if (p0 + lane < NPATHS) out[p0 + lane] = t > 0.0f ? t : 0.0f;
  }
}

// ---------------- host ----------------
extern "C" void kernel_launch(void* const* d_in, const int* in_sizes, int n_in,
                              void* d_out, int out_size, void* d_ws, size_t ws_size,
                              hipStream_t stream) {
  const float* cap     = (const float*)d_in[0];
  const float* traffic = (const float*)d_in[1];
  const int*   links   = (const int*)d_in[2];
  const float* pWx = (const float*)d_in[5];
  const float* pWh = (const float*)d_in[6];
  const float* pb  = (const float*)d_in[7];
  const float* eWx = (const float*)d_in[8];
  const float* eWh = (const float*)d_in[9];
  const float* eb  = (const float*)d_in[10];
  const float* W1  = (const float*)d_in[11];
  const float* b1  = (const float*)d_in[12];
  const float* W2  = (const float*)d_in[13];
  const float* b2  = (const float*)d_in[14];
  const float* W3  = (const float*)d_in[15];
  const float* b3  = (const float*)d_in[16];
  float* out = (float*)d_out;

  uint32_t k1a, k1b, k2a, k2b;
  threefry2x32(0u, 1u, 0u, 0u, k1a, k1b);
  threefry2x32(0u, 1u, 0u, 1u, k2a, k2b);

  const size_t n_link = (size_t)NLINKS * DD;
  const size_t n_seq  = (size_t)NPATHS * LSEQ * DD;
  const size_t n_gx   = (size_t)NLINKS * GW;

  float* link_state = (float*)d_ws;
  float* seq_h      = link_state + n_link;
  float* gx         = seq_h + n_seq;
  int*   counts     = (int*)(gx + n_gx);
  int*   row_start  = counts + NLINKS;
  int*   cursor     = row_start + NLINKS;
  int*   edges      = cursor + NLINKS;

  init_gather_kernel<<<(NLINKS * DD + 255) / 256, 256, 0, stream>>>(
      cap, traffic, link_state, seq_h, counts);
  csr_hist_kernel<<<(NEDGE + 255) / 256, 256, 0, stream>>>(links, counts);
  csr_scan_kernel<<<1, 1024, 0, stream>>>(counts, row_start, cursor);
  csr_fill_kernel<<<(NEDGE + 255) / 256, 256, 0, stream>>>(links, cursor, edges);

  for (int it = 0; it < TITER; ++it) {
    gx_kernel<<<NB, 512, 0, stream>>>(link_state, pWx, pb, gx);
    path_gru_v9_kernel<<<NB, 1024, 0, stream>>>(gx, seq_h, links, pWh);
    link_gru_v9_kernel<<<NB, 1024, 0, stream>>>(link_state, seq_h,
                                                row_start, cursor, edges,
                                                eWx, eWh, eb);
  }
  mlp_v8_kernel<<<NB, 1024, 0, stream>>>(
      (const float4*)seq_h + 7 * 16, LSEQ * 16,
      W1, b1, W2, b2, W3, b3, out, k1a, k1b, k2a, k2b);
}